// Round 7
// baseline (2812.402 us; speedup 1.0000x reference)
//
#include <hip/hip_runtime.h>
#include <math.h>

#define TT   24
#define NN   10000
#define DIN  128
#define H1C  256
#define H2C  128
#define OUTD 100
#define FLATSZ (NN*H2C)

typedef _Float16 f16;
typedef _Float16 f16x2 __attribute__((ext_vector_type(2)));
typedef _Float16 f16x4 __attribute__((ext_vector_type(4)));
typedef _Float16 f16x8 __attribute__((ext_vector_type(8)));
typedef float    f32x4 __attribute__((ext_vector_type(4)));

__device__ __forceinline__ float sigmoidf_(float x){ return 1.0f/(1.0f+expf(-x)); }

// ---------------- small utility kernels ----------------

__global__ __launch_bounds__(256) void zero16_kernel(uint4* __restrict__ p, int n16){
  int i = blockIdx.x*256 + threadIdx.x;
  if (i < n16) p[i] = make_uint4(0u,0u,0u,0u);
}

__global__ __launch_bounds__(256) void cast_f16_kernel(const float4* __restrict__ in,
                                                       f16x4* __restrict__ out, int n4){
  int i = blockIdx.x*256 + threadIdx.x;
  if (i < n4){
    float4 v = in[i];
    f16x4 o; o[0]=(f16)v.x; o[1]=(f16)v.y; o[2]=(f16)v.z; o[3]=(f16)v.w;
    out[i] = o;
  }
}

__global__ __launch_bounds__(256) void init_kernel(int* __restrict__ cnt, int* __restrict__ cursor,
                                                   float* __restrict__ logits, int n){
  int i = blockIdx.x*256 + threadIdx.x;
  if (i < n){ cnt[i] = 0; cursor[i] = 0; }
  if (i < OUTD) logits[i] = 0.0f;
}

__global__ __launch_bounds__(256) void count_kernel(const int* __restrict__ ei, int* __restrict__ cnt, int E){
  int e = blockIdx.x*256 + threadIdx.x;
  if (e < E) atomicAdd(&cnt[ei[E + e]], 1);
}

__global__ __launch_bounds__(256) void dis_kernel(const int* __restrict__ cnt, float* __restrict__ dis, int n){
  int i = blockIdx.x*256 + threadIdx.x;
  if (i < n) dis[i] = rsqrtf((float)(cnt[i] + 1));   // +1 self-loop
}

__global__ __launch_bounds__(256) void scan_kernel(const int* __restrict__ cnt, int* __restrict__ off, int n){
  __shared__ int sums[256];
  const int tid = threadIdx.x;
  const int CH  = 40;                  // 256*40 = 10240 >= NN
  const int base = tid*CH;
  int s = 0;
  for (int i = 0; i < CH; ++i){ int idx = base + i; if (idx < n) s += cnt[idx]; }
  sums[tid] = s; __syncthreads();
  for (int d = 1; d < 256; d <<= 1){
    int v = (tid >= d) ? sums[tid - d] : 0;
    __syncthreads();
    sums[tid] += v;
    __syncthreads();
  }
  int run = (tid == 0) ? 0 : sums[tid - 1];
  for (int i = 0; i < CH; ++i){
    int idx = base + i;
    if (idx < n){ off[idx] = run; run += cnt[idx]; }
  }
  if (tid == 0) off[n] = sums[255];
}

// packed edge record: .x = source row, .y = bitcast(norm weight)
__global__ __launch_bounds__(256) void scatter_kernel(const int* __restrict__ ei, const float* __restrict__ dis,
                                                      const int* __restrict__ off, int* __restrict__ cursor,
                                                      int2* __restrict__ pe, int E){
  int e = blockIdx.x*256 + threadIdx.x;
  if (e < E){
    int r = ei[e];
    int c = ei[E + e];
    int pos = off[c] + atomicAdd(&cursor[c], 1);
    pe[pos] = make_int2(r, __float_as_int(dis[r]*dis[c]));
  }
}

// ---------------- MFMA GEMM, fp32 A (in-register cvt): C = A @ W^T, f16 out ----------------
// Block 256 thr = 4 waves (2Mx2N), wave 64x64, block 128x128.
template<int K>
__global__ __launch_bounds__(256) void gemm_f32a_kernel(
    const float* __restrict__ A, const f16* __restrict__ W,
    f16* __restrict__ C, int M, int N)
{
  const int lane = threadIdx.x & 63;
  const int wave = threadIdx.x >> 6;
  const int wm = wave >> 1, wc = wave & 1;
  const int m_base = blockIdx.x*128 + wm*64;
  const int n_base = blockIdx.y*128 + wc*64;
  const int lr = lane & 15;
  const int lk = (lane >> 4) * 8;
  f32x4 acc[4][4] = {};
  const float* aptr[4]; const f16* bptr[4];
  #pragma unroll
  for (int mi = 0; mi < 4; ++mi){
    int r = m_base + mi*16 + lr; if (r >= M) r = M - 1;
    aptr[mi] = A + (size_t)r*K + lk;
  }
  #pragma unroll
  for (int ci = 0; ci < 4; ++ci){
    int c = n_base + ci*16 + lr;
    bptr[ci] = W + (size_t)c*K + lk;
  }
  #pragma unroll
  for (int k0 = 0; k0 < K; k0 += 32){
    f16x8 a[4], b[4];
    #pragma unroll
    for (int mi = 0; mi < 4; ++mi){
      const float4 v0 = *(const float4*)(aptr[mi] + k0);
      const float4 v1 = *(const float4*)(aptr[mi] + k0 + 4);
      f16x8 t;
      t[0]=(f16)v0.x; t[1]=(f16)v0.y; t[2]=(f16)v0.z; t[3]=(f16)v0.w;
      t[4]=(f16)v1.x; t[5]=(f16)v1.y; t[6]=(f16)v1.z; t[7]=(f16)v1.w;
      a[mi] = t;
    }
    #pragma unroll
    for (int ci = 0; ci < 4; ++ci) b[ci] = *(const f16x8*)(bptr[ci] + k0);
    #pragma unroll
    for (int mi = 0; mi < 4; ++mi)
      #pragma unroll
      for (int ci = 0; ci < 4; ++ci)
        acc[mi][ci] = __builtin_amdgcn_mfma_f32_16x16x32_f16(a[mi], b[ci], acc[mi][ci], 0, 0, 0);
  }
  const int r0 = (lane >> 4)*4;     // C/D: row=(lane>>4)*4+reg, col=lane&15
  #pragma unroll
  for (int mi = 0; mi < 4; ++mi){
    #pragma unroll
    for (int r = 0; r < 4; ++r){
      const int row = m_base + mi*16 + r0 + r;
      if (row < M){
        #pragma unroll
        for (int ci = 0; ci < 4; ++ci)
          C[(size_t)row*N + n_base + ci*16 + lr] = (f16)acc[mi][ci][r];
      }
    }
  }
}

// ---------------- MFMA GEMM, f16 A: C = A @ W^T, f16 out ----------------
template<int K>
__global__ __launch_bounds__(256) void gemm_f16_kernel(
    const f16* __restrict__ A, const f16* __restrict__ W,
    f16* __restrict__ C, int M, int N)
{
  const int lane = threadIdx.x & 63;
  const int wave = threadIdx.x >> 6;
  const int wm = wave >> 1, wc = wave & 1;
  const int m_base = blockIdx.x*128 + wm*64;
  const int n_base = blockIdx.y*128 + wc*64;
  const int lr = lane & 15;
  const int lk = (lane >> 4) * 8;
  f32x4 acc[4][4] = {};
  const f16* aptr[4]; const f16* bptr[4];
  #pragma unroll
  for (int mi = 0; mi < 4; ++mi){
    int r = m_base + mi*16 + lr; if (r >= M) r = M - 1;
    aptr[mi] = A + (size_t)r*K + lk;
  }
  #pragma unroll
  for (int ci = 0; ci < 4; ++ci){
    int c = n_base + ci*16 + lr;
    bptr[ci] = W + (size_t)c*K + lk;
  }
  #pragma unroll
  for (int k0 = 0; k0 < K; k0 += 32){
    f16x8 a[4], b[4];
    #pragma unroll
    for (int mi = 0; mi < 4; ++mi) a[mi] = *(const f16x8*)(aptr[mi] + k0);
    #pragma unroll
    for (int ci = 0; ci < 4; ++ci) b[ci] = *(const f16x8*)(bptr[ci] + k0);
    #pragma unroll
    for (int mi = 0; mi < 4; ++mi)
      #pragma unroll
      for (int ci = 0; ci < 4; ++ci)
        acc[mi][ci] = __builtin_amdgcn_mfma_f32_16x16x32_f16(a[mi], b[ci], acc[mi][ci], 0, 0, 0);
  }
  const int r0 = (lane >> 4)*4;
  #pragma unroll
  for (int mi = 0; mi < 4; ++mi){
    #pragma unroll
    for (int r = 0; r < 4; ++r){
      const int row = m_base + mi*16 + r0 + r;
      if (row < M){
        #pragma unroll
        for (int ci = 0; ci < 4; ++ci)
          C[(size_t)row*N + n_base + ci*16 + lr] = (f16)acc[mi][ci][r];
      }
    }
  }
}

// ---------------- GRU step (GI hoisted): gh = h @ Whh^T (3 gates) + gate combine ----------------
// Wave tile 64 rows x 32 cols x 3 gates (24 MFMA / 10 frag-loads per K-iter).
// Block = 2x2 waves = 128 rows x 64 cols. grid ((M+127)/128, H/64).
template<int H>
__global__ __launch_bounds__(256) void gru_step_kernel(
    const f16* __restrict__ h16, const float* __restrict__ h32,
    const f16* __restrict__ W16,            // (3H, H) row-major f16
    const f16* __restrict__ GI,             // (M, 3H) f16, no bias
    const float* __restrict__ bih, const float* __restrict__ bhh,  // (3H)
    float* __restrict__ o32, f16* __restrict__ o16, int M)
{
  const int lane = threadIdx.x & 63;
  const int wave = threadIdx.x >> 6;
  const int wm = wave >> 1, wc = wave & 1;
  const int m_base = blockIdx.x*128 + wm*64;
  const int c_base = blockIdx.y*64 + wc*32;
  const int lr = lane & 15;
  const int lk = (lane >> 4)*8;
  const int r0 = (lane >> 4)*4;

  f32x4 acc[4][2][3] = {};
  const f16* aptr[4]; const f16* bptr[2][3];
  #pragma unroll
  for (int mi = 0; mi < 4; ++mi){
    int r = m_base + mi*16 + lr; if (r >= M) r = M - 1;
    aptr[mi] = h16 + (size_t)r*H + lk;
  }
  int colv[2];
  #pragma unroll
  for (int ci = 0; ci < 2; ++ci){
    const int col = c_base + ci*16 + lr;
    colv[ci] = col;
    #pragma unroll
    for (int g = 0; g < 3; ++g)
      bptr[ci][g] = W16 + (size_t)(g*H + col)*H + lk;
  }
  #pragma unroll
  for (int k0 = 0; k0 < H; k0 += 32){
    f16x8 a[4], b[2][3];
    #pragma unroll
    for (int mi = 0; mi < 4; ++mi) a[mi] = *(const f16x8*)(aptr[mi] + k0);
    #pragma unroll
    for (int ci = 0; ci < 2; ++ci)
      #pragma unroll
      for (int g = 0; g < 3; ++g) b[ci][g] = *(const f16x8*)(bptr[ci][g] + k0);
    #pragma unroll
    for (int mi = 0; mi < 4; ++mi)
      #pragma unroll
      for (int ci = 0; ci < 2; ++ci){
        acc[mi][ci][0] = __builtin_amdgcn_mfma_f32_16x16x32_f16(a[mi], b[ci][0], acc[mi][ci][0], 0,0,0);
        acc[mi][ci][1] = __builtin_amdgcn_mfma_f32_16x16x32_f16(a[mi], b[ci][1], acc[mi][ci][1], 0,0,0);
        acc[mi][ci][2] = __builtin_amdgcn_mfma_f32_16x16x32_f16(a[mi], b[ci][2], acc[mi][ci][2], 0,0,0);
      }
  }
  float bR[2], bZ[2], bNi[2], bNh[2];
  #pragma unroll
  for (int ci = 0; ci < 2; ++ci){
    bR[ci]  = bih[colv[ci]]       + bhh[colv[ci]];
    bZ[ci]  = bih[H+colv[ci]]     + bhh[H+colv[ci]];
    bNi[ci] = bih[2*H+colv[ci]];
    bNh[ci] = bhh[2*H+colv[ci]];
  }
  #pragma unroll
  for (int mi = 0; mi < 4; ++mi){
    #pragma unroll
    for (int r = 0; r < 4; ++r){
      const int row = m_base + mi*16 + r0 + r;
      if (row >= M) continue;
      const f16* gi = GI + (size_t)row*3*H;
      #pragma unroll
      for (int ci = 0; ci < 2; ++ci){
        const int col = colv[ci];
        const float gr = (float)gi[col]     + acc[mi][ci][0][r] + bR[ci];
        const float gz = (float)gi[H+col]   + acc[mi][ci][1][r] + bZ[ci];
        const float rg = sigmoidf_(gr);
        const float zg = sigmoidf_(gz);
        const float ng = tanhf((float)gi[2*H+col] + bNi[ci] + rg*(acc[mi][ci][2][r] + bNh[ci]));
        const float hp = h32[(size_t)row*H + col];
        const float hv = (1.0f - zg)*ng + zg*hp;
        o32[(size_t)row*H + col] = hv;
        o16[(size_t)row*H + col] = (f16)hv;
      }
    }
  }
}

// ---------------- batched graph conv over all t (f16x4 gather, packed edges, XCD-pinned) ----------------
// grid = TT*NN 1D. xcd = b&7 owns t in {xcd, xcd+8, xcd+16}. 64 thr, 8B/lane covers 512B row.
__global__ __launch_bounds__(64) void conv1_kernel(
    const f16* __restrict__ hall, const int2* __restrict__ pe,
    const int* __restrict__ off, const float* __restrict__ dis,
    const float* __restrict__ bias, f16* __restrict__ outall)
{
  const int b   = blockIdx.x;
  const int xcd = b & 7;
  const int j   = b >> 3;          // 0 .. 3*NN-1
  const int tq  = j / NN;          // 0..2
  const int i   = j - tq*NN;
  const int t   = xcd + 8*tq;
  const int f   = threadIdx.x;     // 0..63 (f16x4 index)
  const f16x4* hp = (const f16x4*)(hall + (size_t)t*NN*H1C);
  const float d = dis[i];
  const f16x4 sv = hp[(size_t)i*64 + f];
  float a0 = d*d*(float)sv[0];
  float a1 = d*d*(float)sv[1];
  float a2 = d*d*(float)sv[2];
  float a3 = d*d*(float)sv[3];
  int e = off[i]; const int e2 = off[i+1];
  for (; e + 8 <= e2; e += 8){
    int2 q[8];
    #pragma unroll
    for (int u = 0; u < 8; ++u) q[u] = pe[e+u];
    #pragma unroll
    for (int u = 0; u < 8; ++u){
      const float w = __int_as_float(q[u].y);
      const f16x4 v = hp[(size_t)q[u].x*64 + f];
      a0 += w*(float)v[0]; a1 += w*(float)v[1];
      a2 += w*(float)v[2]; a3 += w*(float)v[3];
    }
  }
  for (; e < e2; ++e){
    const int2 q = pe[e];
    const float w = __int_as_float(q.y);
    const f16x4 v = hp[(size_t)q.x*64 + f];
    a0 += w*(float)v[0]; a1 += w*(float)v[1];
    a2 += w*(float)v[2]; a3 += w*(float)v[3];
  }
  const float4 bb = ((const float4*)bias)[f];
  a0 = fmaxf(a0 + bb.x, 0.0f);
  a1 = fmaxf(a1 + bb.y, 0.0f);
  a2 = fmaxf(a2 + bb.z, 0.0f);
  a3 = fmaxf(a3 + bb.w, 0.0f);
  f16x4 o; o[0]=(f16)a0; o[1]=(f16)a1; o[2]=(f16)a2; o[3]=(f16)a3;
  ((f16x4*)(outall + (size_t)t*NN*H1C))[(size_t)i*64 + f] = o;
}

// conv2: H=128, single t, fp32 input (final h2 state), no relu, fp32 out
__global__ __launch_bounds__(64) void conv2_kernel(
    const float* __restrict__ h, const int2* __restrict__ pe,
    const int* __restrict__ off, const float* __restrict__ dis,
    const float* __restrict__ bias, float* __restrict__ out)
{
  const int i = blockIdx.x;
  const int f = threadIdx.x;            // 0..63 (float2 index)
  const float2* hp = (const float2*)h;
  const float d = dis[i];
  const float2 sv = hp[(size_t)i*64 + f];
  float a0 = d*d*sv.x;
  float a1 = d*d*sv.y;
  int e = off[i]; const int e2 = off[i+1];
  for (; e + 4 <= e2; e += 4){
    int2 q[4];
    #pragma unroll
    for (int u = 0; u < 4; ++u) q[u] = pe[e+u];
    #pragma unroll
    for (int u = 0; u < 4; ++u){
      const float w = __int_as_float(q[u].y);
      const float2 v = hp[(size_t)q[u].x*64 + f];
      a0 += w*v.x; a1 += w*v.y;
    }
  }
  for (; e < e2; ++e){
    const int2 q = pe[e];
    const float w = __int_as_float(q.y);
    const float2 v = hp[(size_t)q.x*64 + f];
    a0 += w*v.x; a1 += w*v.y;
  }
  const float2 bb = ((const float2*)bias)[f];
  ((float2*)out)[(size_t)i*64 + f] = make_float2(a0 + bb.x, a1 + bb.y);
}

// ---------------- final dense + softmax ----------------
__global__ __launch_bounds__(256) void dense_kernel(const float* __restrict__ flat,
    const float* __restrict__ linW, float* __restrict__ logits)
{
  const int j   = blockIdx.x;
  const int tid = threadIdx.x;
  const int Q4  = FLATSZ/4;                  // 320000
  const int CH4 = Q4/16;                     // 20000 (gridDim.y == 16)
  const int s4  = blockIdx.y*CH4;
  const int e4  = s4 + CH4;
  const float4* w4 = (const float4*)&linW[(size_t)j*FLATSZ];
  const float4* f4 = (const float4*)flat;
  float part = 0.0f;
  for (int i = s4 + tid; i < e4; i += 256){
    const float4 a = w4[i];
    const float4 b = f4[i];
    part += a.x*b.x + a.y*b.y + a.z*b.z + a.w*b.w;
  }
  __shared__ float red[256];
  red[tid] = part; __syncthreads();
  for (int s = 128; s > 0; s >>= 1){
    if (tid < s) red[tid] += red[tid + s];
    __syncthreads();
  }
  if (tid == 0) atomicAdd(&logits[j], red[0]);
}

__global__ __launch_bounds__(128) void softmax_kernel(const float* __restrict__ logits,
    const float* __restrict__ linb, float* __restrict__ out)
{
  __shared__ float red[128];
  const int tid = threadIdx.x;
  const float v = (tid < OUTD) ? logits[tid] + linb[tid] : -INFINITY;
  red[tid] = v; __syncthreads();
  for (int s = 64; s > 0; s >>= 1){
    if (tid < s) red[tid] = fmaxf(red[tid], red[tid + s]);
    __syncthreads();
  }
  const float mx = red[0]; __syncthreads();
  const float e = (tid < OUTD) ? expf(v - mx) : 0.0f;
  red[tid] = e; __syncthreads();
  for (int s = 64; s > 0; s >>= 1){
    if (tid < s) red[tid] += red[tid + s];
    __syncthreads();
  }
  const float inv = 1.0f/red[0];
  if (tid < OUTD) out[tid] = e*inv;
}

// ---------------- launch ----------------

extern "C" void kernel_launch(void* const* d_in, const int* in_sizes, int n_in,
                              void* d_out, int out_size, void* d_ws, size_t ws_size,
                              hipStream_t stream)
{
  const float* x     = (const float*)d_in[0];
  const int*   ei    = (const int*)  d_in[1];
  const float* W_ih1 = (const float*)d_in[2];
  const float* W_hh1 = (const float*)d_in[3];
  const float* b_ih1 = (const float*)d_in[4];
  const float* b_hh1 = (const float*)d_in[5];
  const float* bias1 = (const float*)d_in[6];
  const float* W_ih2 = (const float*)d_in[7];
  const float* W_hh2 = (const float*)d_in[8];
  const float* b_ih2 = (const float*)d_in[9];
  const float* b_hh2 = (const float*)d_in[10];
  const float* bias2 = (const float*)d_in[11];
  const float* lin_W = (const float*)d_in[12];
  const float* lin_b = (const float*)d_in[13];
  float* out = (float*)d_out;
  const int E = in_sizes[1]/2;
  (void)n_in; (void)out_size; (void)ws_size;

  char* p = (char*)d_ws;
  auto alloc = [&](size_t bytes)->void* {
    void* r = (void*)p;
    p += (bytes + 255) & ~(size_t)255;
    return r;
  };
  int*   cnt    = (int*)  alloc((size_t)NN*4);
  int*   cursor = (int*)  alloc((size_t)NN*4);
  int*   offs   = (int*)  alloc((size_t)(NN+1)*4);
  float* dis    = (float*)alloc((size_t)NN*4);
  int2*  pe     = (int2*) alloc((size_t)E*8);
  f16*   gi1    = (f16*)  alloc((size_t)TT*NN*(3*H1C)*2);   // 369 MB; aliased after chain1:
  f16*   x2all  = gi1;                                      //   123 MB (TT*NN*H1C)
  f16*   gi2all = gi1 + (size_t)TT*NN*H1C;                  //   184 MB (TT*NN*3*H2C)
  f16*   h1all  = (f16*)  alloc((size_t)TT*NN*H1C*2);       // 123 MB
  // zeroed region start:
  f16*   zbuf   = (f16*)  alloc((size_t)NN*H1C*2);
  f16*   h2f16a = (f16*)  alloc((size_t)NN*H2C*2);
  float* h1s32a = (float*)alloc((size_t)NN*H1C*4);
  float* h2s32a = (float*)alloc((size_t)NN*H2C*4);
  char*  zend   = p;
  // zeroed region end
  f16*   h2f16b = (f16*)  alloc((size_t)NN*H2C*2);
  float* h1s32b = (float*)alloc((size_t)NN*H1C*4);
  float* h2s32b = (float*)alloc((size_t)NN*H2C*4);
  float* out2   = (float*)alloc((size_t)NN*H2C*4);
  f16*   wih1h  = (f16*)  alloc((size_t)3*H1C*DIN*2);
  f16*   whh1h  = (f16*)  alloc((size_t)3*H1C*H1C*2);
  f16*   wih2h  = (f16*)  alloc((size_t)3*H2C*H1C*2);
  f16*   whh2h  = (f16*)  alloc((size_t)3*H2C*H2C*2);
  float* logits = (float*)alloc((size_t)OUTD*4);

  // ---- graph preprocessing ----
  init_kernel   <<<(NN+255)/256, 256, 0, stream>>>(cnt, cursor, logits, NN);
  count_kernel  <<<(E+255)/256, 256, 0, stream>>>(ei, cnt, E);
  dis_kernel    <<<(NN+255)/256, 256, 0, stream>>>(cnt, dis, NN);
  scan_kernel   <<<1, 256, 0, stream>>>(cnt, offs, NN);
  scatter_kernel<<<(E+255)/256, 256, 0, stream>>>(ei, dis, offs, cursor, pe, E);

  // ---- zero initial states (contiguous region) ----
  {
    const int n16 = (int)((zend - (char*)zbuf)/16);
    zero16_kernel<<<(n16+255)/256, 256, 0, stream>>>((uint4*)zbuf, n16);
  }

  // ---- f16 weight casts ----
  cast_f16_kernel<<<((3*H1C*DIN/4)+255)/256, 256, 0, stream>>>((const float4*)W_ih1, (f16x4*)wih1h, 3*H1C*DIN/4);
  cast_f16_kernel<<<((3*H1C*H1C/4)+255)/256, 256, 0, stream>>>((const float4*)W_hh1, (f16x4*)whh1h, 3*H1C*H1C/4);
  cast_f16_kernel<<<((3*H2C*H1C/4)+255)/256, 256, 0, stream>>>((const float4*)W_ih2, (f16x4*)wih2h, 3*H2C*H1C/4);
  cast_f16_kernel<<<((3*H2C*H2C/4)+255)/256, 256, 0, stream>>>((const float4*)W_hh2, (f16x4*)whh2h, 3*H2C*H2C/4);

  // ---- GI1 for all t: (TT*NN,128) x (768,128)^T ----
  gemm_f32a_kernel<DIN><<<dim3(TT*NN/128, (3*H1C)/128), 256, 0, stream>>>(x, wih1h, gi1, TT*NN, 3*H1C);

  const int GB = (NN + 127)/128;   // 79

  // ---- layer-1 GRU chain (per-t, GI hoisted) ----
  {
    float* h32c = h1s32a; float* h32n = h1s32b;
    for (int t = 0; t < TT; ++t){
      const f16* hprev16 = (t == 0) ? zbuf : (h1all + (size_t)(t-1)*NN*H1C);
      gru_step_kernel<H1C><<<dim3(GB, H1C/64), 256, 0, stream>>>(
          hprev16, h32c, whh1h, gi1 + (size_t)t*NN*(3*H1C), b_ih1, b_hh1,
          h32n, h1all + (size_t)t*NN*H1C, NN);
      float* tmp = h32c; h32c = h32n; h32n = tmp;
    }
  }

  // ---- batched conv1 (XCD-pinned, f16x4, packed edges) ----
  conv1_kernel<<<TT*NN, 64, 0, stream>>>(h1all, pe, offs, dis, bias1, x2all);

  // ---- GI2 batched: (TT*NN,256) x (384,256)^T ----
  gemm_f16_kernel<H1C><<<dim3(TT*NN/128, (3*H2C)/128), 256, 0, stream>>>(x2all, wih2h, gi2all, TT*NN, 3*H2C);

  // ---- layer-2 GRU chain ----
  float* h2final;
  {
    float* h32c = h2s32a; float* h32n = h2s32b;
    f16*   h16c = h2f16a; f16*   h16n = h2f16b;
    for (int t = 0; t < TT; ++t){
      gru_step_kernel<H2C><<<dim3(GB, H2C/64), 256, 0, stream>>>(
          h16c, h32c, whh2h, gi2all + (size_t)t*NN*(3*H2C), b_ih2, b_hh2,
          h32n, h16n, NN);
      float* tf = h32c; h32c = h32n; h32n = tf;
      f16*   th = h16c; h16c = h16n; h16n = th;
    }
    h2final = h32c;   // holds t=23 fp32 state after even swaps
  }

  conv2_kernel<<<NN, 64, 0, stream>>>(h2final, pe, offs, dis, bias2, out2);
  dense_kernel<<<dim3(OUTD, 16), 256, 0, stream>>>(out2, lin_W, logits);
  softmax_kernel<<<1, 128, 0, stream>>>(logits, lin_b, out);
}

// Round 8
// 2624.137 us; speedup vs baseline: 1.0717x; 1.0717x over previous
//
#include <hip/hip_runtime.h>
#include <math.h>

#define TT   24
#define NN   10000
#define DIN  128
#define H1C  256
#define H2C  128
#define OUTD 100
#define FLATSZ (NN*H2C)

typedef _Float16 f16;
typedef _Float16 f16x2 __attribute__((ext_vector_type(2)));
typedef _Float16 f16x4 __attribute__((ext_vector_type(4)));
typedef _Float16 f16x8 __attribute__((ext_vector_type(8)));
typedef float    f32x4 __attribute__((ext_vector_type(4)));

__device__ __forceinline__ float sigmoidf_(float x){ return 1.0f/(1.0f+expf(-x)); }

// ---------------- small utility kernels ----------------

__global__ __launch_bounds__(256) void cast_f16_kernel(const float4* __restrict__ in,
                                                       f16x4* __restrict__ out, int n4){
  int i = blockIdx.x*256 + threadIdx.x;
  if (i < n4){
    float4 v = in[i];
    f16x4 o; o[0]=(f16)v.x; o[1]=(f16)v.y; o[2]=(f16)v.z; o[3]=(f16)v.w;
    out[i] = o;
  }
}

__global__ __launch_bounds__(256) void init_kernel(int* __restrict__ cnt, int* __restrict__ cursor,
                                                   float* __restrict__ logits, int n){
  int i = blockIdx.x*256 + threadIdx.x;
  if (i < n){ cnt[i] = 0; cursor[i] = 0; }
  if (i < OUTD) logits[i] = 0.0f;
}

__global__ __launch_bounds__(256) void count_kernel(const int* __restrict__ ei, int* __restrict__ cnt, int E){
  int e = blockIdx.x*256 + threadIdx.x;
  if (e < E) atomicAdd(&cnt[ei[E + e]], 1);
}

__global__ __launch_bounds__(256) void dis_kernel(const int* __restrict__ cnt, float* __restrict__ dis, int n){
  int i = blockIdx.x*256 + threadIdx.x;
  if (i < n) dis[i] = rsqrtf((float)(cnt[i] + 1));   // +1 self-loop
}

__global__ __launch_bounds__(256) void scan_kernel(const int* __restrict__ cnt, int* __restrict__ off, int n){
  __shared__ int sums[256];
  const int tid = threadIdx.x;
  const int CH  = 40;                  // 256*40 = 10240 >= NN
  const int base = tid*CH;
  int s = 0;
  for (int i = 0; i < CH; ++i){ int idx = base + i; if (idx < n) s += cnt[idx]; }
  sums[tid] = s; __syncthreads();
  for (int d = 1; d < 256; d <<= 1){
    int v = (tid >= d) ? sums[tid - d] : 0;
    __syncthreads();
    sums[tid] += v;
    __syncthreads();
  }
  int run = (tid == 0) ? 0 : sums[tid - 1];
  for (int i = 0; i < CH; ++i){
    int idx = base + i;
    if (idx < n){ off[idx] = run; run += cnt[idx]; }
  }
  if (tid == 0) off[n] = sums[255];
}

// packed edge record: .x = source row, .y = bitcast(norm weight)
__global__ __launch_bounds__(256) void scatter_kernel(const int* __restrict__ ei, const float* __restrict__ dis,
                                                      const int* __restrict__ off, int* __restrict__ cursor,
                                                      int2* __restrict__ pe, int E){
  int e = blockIdx.x*256 + threadIdx.x;
  if (e < E){
    int r = ei[e];
    int c = ei[E + e];
    int pos = off[c] + atomicAdd(&cursor[c], 1);
    pe[pos] = make_int2(r, __float_as_int(dis[r]*dis[c]));
  }
}

// ---------------- MFMA GEMM, fp32 A (in-register cvt): C = A @ W^T, f16 out ----------------
template<int K>
__global__ __launch_bounds__(256) void gemm_f32a_kernel(
    const float* __restrict__ A, const f16* __restrict__ W,
    f16* __restrict__ C, int M, int N)
{
  const int lane = threadIdx.x & 63;
  const int wave = threadIdx.x >> 6;
  const int wm = wave >> 1, wc = wave & 1;
  const int m_base = blockIdx.x*128 + wm*64;
  const int n_base = blockIdx.y*128 + wc*64;
  const int lr = lane & 15;
  const int lk = (lane >> 4) * 8;
  f32x4 acc[4][4] = {};
  const float* aptr[4]; const f16* bptr[4];
  #pragma unroll
  for (int mi = 0; mi < 4; ++mi){
    int r = m_base + mi*16 + lr; if (r >= M) r = M - 1;
    aptr[mi] = A + (size_t)r*K + lk;
  }
  #pragma unroll
  for (int ci = 0; ci < 4; ++ci){
    int c = n_base + ci*16 + lr;
    bptr[ci] = W + (size_t)c*K + lk;
  }
  #pragma unroll
  for (int k0 = 0; k0 < K; k0 += 32){
    f16x8 a[4], b[4];
    #pragma unroll
    for (int mi = 0; mi < 4; ++mi){
      const float4 v0 = *(const float4*)(aptr[mi] + k0);
      const float4 v1 = *(const float4*)(aptr[mi] + k0 + 4);
      f16x8 t;
      t[0]=(f16)v0.x; t[1]=(f16)v0.y; t[2]=(f16)v0.z; t[3]=(f16)v0.w;
      t[4]=(f16)v1.x; t[5]=(f16)v1.y; t[6]=(f16)v1.z; t[7]=(f16)v1.w;
      a[mi] = t;
    }
    #pragma unroll
    for (int ci = 0; ci < 4; ++ci) b[ci] = *(const f16x8*)(bptr[ci] + k0);
    #pragma unroll
    for (int mi = 0; mi < 4; ++mi)
      #pragma unroll
      for (int ci = 0; ci < 4; ++ci)
        acc[mi][ci] = __builtin_amdgcn_mfma_f32_16x16x32_f16(a[mi], b[ci], acc[mi][ci], 0, 0, 0);
  }
  const int r0 = (lane >> 4)*4;
  #pragma unroll
  for (int mi = 0; mi < 4; ++mi){
    #pragma unroll
    for (int r = 0; r < 4; ++r){
      const int row = m_base + mi*16 + r0 + r;
      if (row < M){
        #pragma unroll
        for (int ci = 0; ci < 4; ++ci)
          C[(size_t)row*N + n_base + ci*16 + lr] = (f16)acc[mi][ci][r];
      }
    }
  }
}

// ---------------- MFMA GEMM, f16 A: C = A @ W^T, f16 out ----------------
template<int K>
__global__ __launch_bounds__(256) void gemm_f16_kernel(
    const f16* __restrict__ A, const f16* __restrict__ W,
    f16* __restrict__ C, int M, int N)
{
  const int lane = threadIdx.x & 63;
  const int wave = threadIdx.x >> 6;
  const int wm = wave >> 1, wc = wave & 1;
  const int m_base = blockIdx.x*128 + wm*64;
  const int n_base = blockIdx.y*128 + wc*64;
  const int lr = lane & 15;
  const int lk = (lane >> 4) * 8;
  f32x4 acc[4][4] = {};
  const f16* aptr[4]; const f16* bptr[4];
  #pragma unroll
  for (int mi = 0; mi < 4; ++mi){
    int r = m_base + mi*16 + lr; if (r >= M) r = M - 1;
    aptr[mi] = A + (size_t)r*K + lk;
  }
  #pragma unroll
  for (int ci = 0; ci < 4; ++ci){
    int c = n_base + ci*16 + lr;
    bptr[ci] = W + (size_t)c*K + lk;
  }
  #pragma unroll
  for (int k0 = 0; k0 < K; k0 += 32){
    f16x8 a[4], b[4];
    #pragma unroll
    for (int mi = 0; mi < 4; ++mi) a[mi] = *(const f16x8*)(aptr[mi] + k0);
    #pragma unroll
    for (int ci = 0; ci < 4; ++ci) b[ci] = *(const f16x8*)(bptr[ci] + k0);
    #pragma unroll
    for (int mi = 0; mi < 4; ++mi)
      #pragma unroll
      for (int ci = 0; ci < 4; ++ci)
        acc[mi][ci] = __builtin_amdgcn_mfma_f32_16x16x32_f16(a[mi], b[ci], acc[mi][ci], 0, 0, 0);
  }
  const int r0 = (lane >> 4)*4;
  #pragma unroll
  for (int mi = 0; mi < 4; ++mi){
    #pragma unroll
    for (int r = 0; r < 4; ++r){
      const int row = m_base + mi*16 + r0 + r;
      if (row < M){
        #pragma unroll
        for (int ci = 0; ci < 4; ++ci)
          C[(size_t)row*N + n_base + ci*16 + lr] = (f16)acc[mi][ci][r];
      }
    }
  }
}

// ---------------- layer-1 GRU chain: ONE kernel, block-local rows, h in LDS ----------------
// Block = 32 rows x 256 cols, 256 thr = 4 waves (wave w owns cols w*64..w*64+63 x 3 gates).
// h state: f16 tile in LDS (row-local across t) + fp32 in registers. GI pre-computed (hoisted).
// Per step: read GI slice + Whh (L2-resident) ; write h1all via coalesced LDS copy.
__global__ __launch_bounds__(256) void gru1_chain_kernel(
    const f16* __restrict__ gi1,      // (TT*NN, 768)
    const f16* __restrict__ Whh,      // (768, 256) row-major f16
    const float* __restrict__ bih, const float* __restrict__ bhh,
    f16* __restrict__ h1all)          // (TT, NN, 256)
{
  constexpr int H  = H1C;             // 256
  constexpr int LP = H + 8;           // 264 f16 pitch: 16B-aligned rows, stride 132 dwords -> 2-way bank alias (free)
  __shared__ __align__(16) f16 hl[32*LP];

  const int tid  = threadIdx.x;
  const int lane = tid & 63;
  const int w    = tid >> 6;          // 0..3 col group
  const int lr   = lane & 15;
  const int lk8  = (lane >> 4)*8;
  const int r0   = (lane >> 4)*4;
  const int row_base = blockIdx.x*32;

  // zero initial h in LDS
  for (int k = tid*8; k < 32*LP; k += 256*8)
    *(f16x8*)&hl[k] = (f16x8){0,0,0,0,0,0,0,0};

  const f16* bp[4][3];
  int colv[4]; float bR[4], bZ[4], bNi[4], bNh[4];
  #pragma unroll
  for (int ci = 0; ci < 4; ++ci){
    const int col = w*64 + ci*16 + lr;
    colv[ci] = col;
    #pragma unroll
    for (int g = 0; g < 3; ++g)
      bp[ci][g] = Whh + (size_t)(g*H + col)*H + lk8;
    bR[ci]  = bih[col]       + bhh[col];
    bZ[ci]  = bih[H+col]     + bhh[H+col];
    bNi[ci] = bih[2*H+col];
    bNh[ci] = bhh[2*H+col];
  }
  const int lrow0 = lr, lrow1 = 16 + lr;

  float hst[2][4][4] = {};   // [mi][rr][ci] fp32 recurrent state (thread-owned, all t)
  __syncthreads();

  for (int t = 0; t < TT; ++t){
    f32x4 acc[2][4][3] = {};   // [mi][ci][gate]
    #pragma unroll
    for (int k0 = 0; k0 < H; k0 += 32){
      f16x8 a0 = *(const f16x8*)&hl[lrow0*LP + k0 + lk8];
      f16x8 a1 = *(const f16x8*)&hl[lrow1*LP + k0 + lk8];
      f16x8 b[4][3];
      #pragma unroll
      for (int ci = 0; ci < 4; ++ci)
        #pragma unroll
        for (int g = 0; g < 3; ++g) b[ci][g] = *(const f16x8*)(bp[ci][g] + k0);
      #pragma unroll
      for (int ci = 0; ci < 4; ++ci)
        #pragma unroll
        for (int g = 0; g < 3; ++g){
          acc[0][ci][g] = __builtin_amdgcn_mfma_f32_16x16x32_f16(a0, b[ci][g], acc[0][ci][g], 0,0,0);
          acc[1][ci][g] = __builtin_amdgcn_mfma_f32_16x16x32_f16(a1, b[ci][g], acc[1][ci][g], 0,0,0);
        }
    }
    __syncthreads();   // all waves done reading hl
    // epilogue: gates + state update, write new h into LDS
    #pragma unroll
    for (int mi = 0; mi < 2; ++mi){
      #pragma unroll
      for (int rr = 0; rr < 4; ++rr){
        const int rl = mi*16 + r0 + rr;
        int grow = row_base + rl; if (grow >= NN) grow = NN - 1;   // clamp (dead rows compute garbage-free copies)
        const f16* gi = gi1 + ((size_t)t*NN + grow)*(3*H);
        #pragma unroll
        for (int ci = 0; ci < 4; ++ci){
          const int col = colv[ci];
          const float gr = (float)gi[col]     + acc[mi][ci][0][rr] + bR[ci];
          const float gz = (float)gi[H+col]   + acc[mi][ci][1][rr] + bZ[ci];
          const float rg = sigmoidf_(gr);
          const float zg = sigmoidf_(gz);
          const float ng = tanhf((float)gi[2*H+col] + bNi[ci] + rg*(acc[mi][ci][2][rr] + bNh[ci]));
          const float hv = (1.0f - zg)*ng + zg*hst[mi][rr][ci];
          hst[mi][rr][ci] = hv;
          hl[rl*LP + col] = (f16)hv;
        }
      }
    }
    __syncthreads();   // writes visible
    // coalesced copy LDS tile -> h1all[t]
    f16* ho = h1all + ((size_t)t*NN + row_base)*H;
    #pragma unroll
    for (int c = 0; c < 4; ++c){
      const int idx = c*256 + tid;          // 0..1023 chunks of 16B
      const int row = idx >> 5, seg = idx & 31;
      if (row_base + row < NN)
        *(f16x8*)&ho[(size_t)row*H + seg*8] = *(const f16x8*)&hl[row*LP + seg*8];
    }
    // next K-loop only READS hl; epilogue writes of t+1 are fenced by its own post-K-loop sync
  }
}

// ---------------- layer-2 GRU chain: ONE kernel, block-local, no per-step global writes ----------------
// Block = 32 rows x 128 cols, 256 thr = 4 waves (wave w owns cols w*32..w*32+31 x 3 gates).
__global__ __launch_bounds__(256) void gru2_chain_kernel(
    const f16* __restrict__ gi2,      // (TT*NN, 384)
    const f16* __restrict__ Whh,      // (384, 128) row-major f16
    const float* __restrict__ bih, const float* __restrict__ bhh,
    float* __restrict__ h2fin)        // (NN, 128) fp32, t=23 only
{
  constexpr int H  = H2C;             // 128
  constexpr int LP = H + 8;           // 136
  __shared__ __align__(16) f16 hl[32*LP];

  const int tid  = threadIdx.x;
  const int lane = tid & 63;
  const int w    = tid >> 6;
  const int lr   = lane & 15;
  const int lk8  = (lane >> 4)*8;
  const int r0   = (lane >> 4)*4;
  const int row_base = blockIdx.x*32;

  for (int k = tid*8; k < 32*LP; k += 256*8)
    *(f16x8*)&hl[k] = (f16x8){0,0,0,0,0,0,0,0};

  const f16* bp[2][3];
  int colv[2]; float bR[2], bZ[2], bNi[2], bNh[2];
  #pragma unroll
  for (int ci = 0; ci < 2; ++ci){
    const int col = w*32 + ci*16 + lr;
    colv[ci] = col;
    #pragma unroll
    for (int g = 0; g < 3; ++g)
      bp[ci][g] = Whh + (size_t)(g*H + col)*H + lk8;
    bR[ci]  = bih[col]       + bhh[col];
    bZ[ci]  = bih[H+col]     + bhh[H+col];
    bNi[ci] = bih[2*H+col];
    bNh[ci] = bhh[2*H+col];
  }
  const int lrow0 = lr, lrow1 = 16 + lr;

  float hst[2][4][2] = {};
  __syncthreads();

  for (int t = 0; t < TT; ++t){
    f32x4 acc[2][2][3] = {};
    #pragma unroll
    for (int k0 = 0; k0 < H; k0 += 32){
      f16x8 a0 = *(const f16x8*)&hl[lrow0*LP + k0 + lk8];
      f16x8 a1 = *(const f16x8*)&hl[lrow1*LP + k0 + lk8];
      f16x8 b[2][3];
      #pragma unroll
      for (int ci = 0; ci < 2; ++ci)
        #pragma unroll
        for (int g = 0; g < 3; ++g) b[ci][g] = *(const f16x8*)(bp[ci][g] + k0);
      #pragma unroll
      for (int ci = 0; ci < 2; ++ci)
        #pragma unroll
        for (int g = 0; g < 3; ++g){
          acc[0][ci][g] = __builtin_amdgcn_mfma_f32_16x16x32_f16(a0, b[ci][g], acc[0][ci][g], 0,0,0);
          acc[1][ci][g] = __builtin_amdgcn_mfma_f32_16x16x32_f16(a1, b[ci][g], acc[1][ci][g], 0,0,0);
        }
    }
    __syncthreads();
    #pragma unroll
    for (int mi = 0; mi < 2; ++mi){
      #pragma unroll
      for (int rr = 0; rr < 4; ++rr){
        const int rl = mi*16 + r0 + rr;
        const int growu = row_base + rl;
        int grow = growu; if (grow >= NN) grow = NN - 1;
        const f16* gi = gi2 + ((size_t)t*NN + grow)*(3*H);
        #pragma unroll
        for (int ci = 0; ci < 2; ++ci){
          const int col = colv[ci];
          const float gr = (float)gi[col]     + acc[mi][ci][0][rr] + bR[ci];
          const float gz = (float)gi[H+col]   + acc[mi][ci][1][rr] + bZ[ci];
          const float rg = sigmoidf_(gr);
          const float zg = sigmoidf_(gz);
          const float ng = tanhf((float)gi[2*H+col] + bNi[ci] + rg*(acc[mi][ci][2][rr] + bNh[ci]));
          const float hv = (1.0f - zg)*ng + zg*hst[mi][rr][ci];
          hst[mi][rr][ci] = hv;
          hl[rl*LP + col] = (f16)hv;
          if (t == TT-1 && growu < NN)
            h2fin[(size_t)growu*H + col] = hv;
        }
      }
    }
    __syncthreads();
  }
}

// ---------------- batched graph conv over all t (f16x4 gather, packed edges, XCD-pinned) ----------------
__global__ __launch_bounds__(64) void conv1_kernel(
    const f16* __restrict__ hall, const int2* __restrict__ pe,
    const int* __restrict__ off, const float* __restrict__ dis,
    const float* __restrict__ bias, f16* __restrict__ outall)
{
  const int b   = blockIdx.x;
  const int xcd = b & 7;
  const int j   = b >> 3;          // 0 .. 3*NN-1
  const int tq  = j / NN;          // 0..2
  const int i   = j - tq*NN;
  const int t   = xcd + 8*tq;
  const int f   = threadIdx.x;     // 0..63 (f16x4 index)
  const f16x4* hp = (const f16x4*)(hall + (size_t)t*NN*H1C);
  const float d = dis[i];
  const f16x4 sv = hp[(size_t)i*64 + f];
  float a0 = d*d*(float)sv[0];
  float a1 = d*d*(float)sv[1];
  float a2 = d*d*(float)sv[2];
  float a3 = d*d*(float)sv[3];
  int e = off[i]; const int e2 = off[i+1];
  for (; e + 8 <= e2; e += 8){
    int2 q[8];
    #pragma unroll
    for (int u = 0; u < 8; ++u) q[u] = pe[e+u];
    #pragma unroll
    for (int u = 0; u < 8; ++u){
      const float wq = __int_as_float(q[u].y);
      const f16x4 v = hp[(size_t)q[u].x*64 + f];
      a0 += wq*(float)v[0]; a1 += wq*(float)v[1];
      a2 += wq*(float)v[2]; a3 += wq*(float)v[3];
    }
  }
  for (; e < e2; ++e){
    const int2 q = pe[e];
    const float wq = __int_as_float(q.y);
    const f16x4 v = hp[(size_t)q.x*64 + f];
    a0 += wq*(float)v[0]; a1 += wq*(float)v[1];
    a2 += wq*(float)v[2]; a3 += wq*(float)v[3];
  }
  const float4 bb = ((const float4*)bias)[f];
  a0 = fmaxf(a0 + bb.x, 0.0f);
  a1 = fmaxf(a1 + bb.y, 0.0f);
  a2 = fmaxf(a2 + bb.z, 0.0f);
  a3 = fmaxf(a3 + bb.w, 0.0f);
  f16x4 o; o[0]=(f16)a0; o[1]=(f16)a1; o[2]=(f16)a2; o[3]=(f16)a3;
  ((f16x4*)(outall + (size_t)t*NN*H1C))[(size_t)i*64 + f] = o;
}

// conv2: H=128, single t, fp32 input (final h2 state), no relu, fp32 out
__global__ __launch_bounds__(64) void conv2_kernel(
    const float* __restrict__ h, const int2* __restrict__ pe,
    const int* __restrict__ off, const float* __restrict__ dis,
    const float* __restrict__ bias, float* __restrict__ out)
{
  const int i = blockIdx.x;
  const int f = threadIdx.x;            // 0..63 (float2 index)
  const float2* hp = (const float2*)h;
  const float d = dis[i];
  const float2 sv = hp[(size_t)i*64 + f];
  float a0 = d*d*sv.x;
  float a1 = d*d*sv.y;
  int e = off[i]; const int e2 = off[i+1];
  for (; e + 4 <= e2; e += 4){
    int2 q[4];
    #pragma unroll
    for (int u = 0; u < 4; ++u) q[u] = pe[e+u];
    #pragma unroll
    for (int u = 0; u < 4; ++u){
      const float wq = __int_as_float(q[u].y);
      const float2 v = hp[(size_t)q[u].x*64 + f];
      a0 += wq*v.x; a1 += wq*v.y;
    }
  }
  for (; e < e2; ++e){
    const int2 q = pe[e];
    const float wq = __int_as_float(q.y);
    const float2 v = hp[(size_t)q.x*64 + f];
    a0 += wq*v.x; a1 += wq*v.y;
  }
  const float2 bb = ((const float2*)bias)[f];
  ((float2*)out)[(size_t)i*64 + f] = make_float2(a0 + bb.x, a1 + bb.y);
}

// ---------------- final dense + softmax ----------------
__global__ __launch_bounds__(256) void dense_kernel(const float* __restrict__ flat,
    const float* __restrict__ linW, float* __restrict__ logits)
{
  const int j   = blockIdx.x;
  const int tid = threadIdx.x;
  const int Q4  = FLATSZ/4;                  // 320000
  const int CH4 = Q4/16;                     // 20000 (gridDim.y == 16)
  const int s4  = blockIdx.y*CH4;
  const int e4  = s4 + CH4;
  const float4* w4 = (const float4*)&linW[(size_t)j*FLATSZ];
  const float4* f4 = (const float4*)flat;
  float part = 0.0f;
  for (int i = s4 + tid; i < e4; i += 256){
    const float4 a = w4[i];
    const float4 b = f4[i];
    part += a.x*b.x + a.y*b.y + a.z*b.z + a.w*b.w;
  }
  __shared__ float red[256];
  red[tid] = part; __syncthreads();
  for (int s = 128; s > 0; s >>= 1){
    if (tid < s) red[tid] += red[tid + s];
    __syncthreads();
  }
  if (tid == 0) atomicAdd(&logits[j], red[0]);
}

__global__ __launch_bounds__(128) void softmax_kernel(const float* __restrict__ logits,
    const float* __restrict__ linb, float* __restrict__ out)
{
  __shared__ float red[128];
  const int tid = threadIdx.x;
  const float v = (tid < OUTD) ? logits[tid] + linb[tid] : -INFINITY;
  red[tid] = v; __syncthreads();
  for (int s = 64; s > 0; s >>= 1){
    if (tid < s) red[tid] = fmaxf(red[tid], red[tid + s]);
    __syncthreads();
  }
  const float mx = red[0]; __syncthreads();
  const float e = (tid < OUTD) ? expf(v - mx) : 0.0f;
  red[tid] = e; __syncthreads();
  for (int s = 64; s > 0; s >>= 1){
    if (tid < s) red[tid] += red[tid + s];
    __syncthreads();
  }
  const float inv = 1.0f/red[0];
  if (tid < OUTD) out[tid] = e*inv;
}

// ---------------- launch ----------------

extern "C" void kernel_launch(void* const* d_in, const int* in_sizes, int n_in,
                              void* d_out, int out_size, void* d_ws, size_t ws_size,
                              hipStream_t stream)
{
  const float* x     = (const float*)d_in[0];
  const int*   ei    = (const int*)  d_in[1];
  const float* W_ih1 = (const float*)d_in[2];
  const float* W_hh1 = (const float*)d_in[3];
  const float* b_ih1 = (const float*)d_in[4];
  const float* b_hh1 = (const float*)d_in[5];
  const float* bias1 = (const float*)d_in[6];
  const float* W_ih2 = (const float*)d_in[7];
  const float* W_hh2 = (const float*)d_in[8];
  const float* b_ih2 = (const float*)d_in[9];
  const float* b_hh2 = (const float*)d_in[10];
  const float* bias2 = (const float*)d_in[11];
  const float* lin_W = (const float*)d_in[12];
  const float* lin_b = (const float*)d_in[13];
  float* out = (float*)d_out;
  const int E = in_sizes[1]/2;
  (void)n_in; (void)out_size; (void)ws_size;

  char* p = (char*)d_ws;
  auto alloc = [&](size_t bytes)->void* {
    void* r = (void*)p;
    p += (bytes + 255) & ~(size_t)255;
    return r;
  };
  int*   cnt    = (int*)  alloc((size_t)NN*4);
  int*   cursor = (int*)  alloc((size_t)NN*4);
  int*   offs   = (int*)  alloc((size_t)(NN+1)*4);
  float* dis    = (float*)alloc((size_t)NN*4);
  int2*  pe     = (int2*) alloc((size_t)E*8);
  f16*   gi1    = (f16*)  alloc((size_t)TT*NN*(3*H1C)*2);   // 369 MB; aliased after chain1:
  f16*   x2all  = gi1;                                      //   123 MB (TT*NN*H1C)
  f16*   gi2all = gi1 + (size_t)TT*NN*H1C;                  //   184 MB (TT*NN*3*H2C)
  f16*   h1all  = (f16*)  alloc((size_t)TT*NN*H1C*2);       // 123 MB
  float* h2fin  = (float*)alloc((size_t)NN*H2C*4);
  float* out2   = (float*)alloc((size_t)NN*H2C*4);
  f16*   wih1h  = (f16*)  alloc((size_t)3*H1C*DIN*2);
  f16*   whh1h  = (f16*)  alloc((size_t)3*H1C*H1C*2);
  f16*   wih2h  = (f16*)  alloc((size_t)3*H2C*H1C*2);
  f16*   whh2h  = (f16*)  alloc((size_t)3*H2C*H2C*2);
  float* logits = (float*)alloc((size_t)OUTD*4);

  // ---- graph preprocessing ----
  init_kernel   <<<(NN+255)/256, 256, 0, stream>>>(cnt, cursor, logits, NN);
  count_kernel  <<<(E+255)/256, 256, 0, stream>>>(ei, cnt, E);
  dis_kernel    <<<(NN+255)/256, 256, 0, stream>>>(cnt, dis, NN);
  scan_kernel   <<<1, 256, 0, stream>>>(cnt, offs, NN);
  scatter_kernel<<<(E+255)/256, 256, 0, stream>>>(ei, dis, offs, cursor, pe, E);

  // ---- f16 weight casts ----
  cast_f16_kernel<<<((3*H1C*DIN/4)+255)/256, 256, 0, stream>>>((const float4*)W_ih1, (f16x4*)wih1h, 3*H1C*DIN/4);
  cast_f16_kernel<<<((3*H1C*H1C/4)+255)/256, 256, 0, stream>>>((const float4*)W_hh1, (f16x4*)whh1h, 3*H1C*H1C/4);
  cast_f16_kernel<<<((3*H2C*H1C/4)+255)/256, 256, 0, stream>>>((const float4*)W_ih2, (f16x4*)wih2h, 3*H2C*H1C/4);
  cast_f16_kernel<<<((3*H2C*H2C/4)+255)/256, 256, 0, stream>>>((const float4*)W_hh2, (f16x4*)whh2h, 3*H2C*H2C/4);

  // ---- GI1 for all t: (TT*NN,128) x (768,128)^T ----
  gemm_f32a_kernel<DIN><<<dim3(TT*NN/128, (3*H1C)/128), 256, 0, stream>>>(x, wih1h, gi1, TT*NN, 3*H1C);

  const int CB = (NN + 31)/32;   // 313

  // ---- layer-1 GRU chain: single kernel, 24 steps inside, block-local ----
  gru1_chain_kernel<<<CB, 256, 0, stream>>>(gi1, whh1h, b_ih1, b_hh1, h1all);

  // ---- batched conv1 (XCD-pinned, f16x4, packed edges) ----
  conv1_kernel<<<TT*NN, 64, 0, stream>>>(h1all, pe, offs, dis, bias1, x2all);

  // ---- GI2 batched: (TT*NN,256) x (384,256)^T ----
  gemm_f16_kernel<H1C><<<dim3(TT*NN/128, (3*H2C)/128), 256, 0, stream>>>(x2all, wih2h, gi2all, TT*NN, 3*H2C);

  // ---- layer-2 GRU chain: single kernel ----
  gru2_chain_kernel<<<CB, 256, 0, stream>>>(gi2all, whh2h, b_ih2, b_hh2, h2fin);

  conv2_kernel<<<NN, 64, 0, stream>>>(h2fin, pe, offs, dis, bias2, out2);
  dense_kernel<<<dim3(OUTD, 16), 256, 0, stream>>>(out2, lin_W, logits);
  softmax_kernel<<<1, 128, 0, stream>>>(logits, lin_b, out);
}

// Round 9
// 2493.558 us; speedup vs baseline: 1.1279x; 1.0524x over previous
//
#include <hip/hip_runtime.h>
#include <math.h>

#define TT   24
#define NN   10000
#define DIN  128
#define H1C  256
#define H2C  128
#define OUTD 100
#define FLATSZ (NN*H2C)

typedef _Float16 f16;
typedef _Float16 f16x4 __attribute__((ext_vector_type(4)));
typedef _Float16 f16x8 __attribute__((ext_vector_type(8)));
typedef float    f32x4 __attribute__((ext_vector_type(4)));

__device__ __forceinline__ float sigmoidf_(float x){ return 1.0f/(1.0f+expf(-x)); }

__device__ __forceinline__ f16x8 cvt8(const float* p){
  const float4 v0 = *(const float4*)p;
  const float4 v1 = *(const float4*)(p + 4);
  f16x8 t;
  t[0]=(f16)v0.x; t[1]=(f16)v0.y; t[2]=(f16)v0.z; t[3]=(f16)v0.w;
  t[4]=(f16)v1.x; t[5]=(f16)v1.y; t[6]=(f16)v1.z; t[7]=(f16)v1.w;
  return t;
}

// ---------------- small utility kernels ----------------

__global__ __launch_bounds__(256) void cast_f16_kernel(const float4* __restrict__ in,
                                                       f16x4* __restrict__ out, int n4){
  int i = blockIdx.x*256 + threadIdx.x;
  if (i < n4){
    float4 v = in[i];
    f16x4 o; o[0]=(f16)v.x; o[1]=(f16)v.y; o[2]=(f16)v.z; o[3]=(f16)v.w;
    out[i] = o;
  }
}

__global__ __launch_bounds__(256) void init_kernel(int* __restrict__ cnt, int* __restrict__ cursor,
                                                   float* __restrict__ logits, int n){
  int i = blockIdx.x*256 + threadIdx.x;
  if (i < n){ cnt[i] = 0; cursor[i] = 0; }
  if (i < OUTD) logits[i] = 0.0f;
}

__global__ __launch_bounds__(256) void count_kernel(const int* __restrict__ ei, int* __restrict__ cnt, int E){
  int e = blockIdx.x*256 + threadIdx.x;
  if (e < E) atomicAdd(&cnt[ei[E + e]], 1);
}

__global__ __launch_bounds__(256) void dis_kernel(const int* __restrict__ cnt, float* __restrict__ dis, int n){
  int i = blockIdx.x*256 + threadIdx.x;
  if (i < n) dis[i] = rsqrtf((float)(cnt[i] + 1));   // +1 self-loop
}

__global__ __launch_bounds__(256) void scan_kernel(const int* __restrict__ cnt, int* __restrict__ off, int n){
  __shared__ int sums[256];
  const int tid = threadIdx.x;
  const int CH  = 40;
  const int base = tid*CH;
  int s = 0;
  for (int i = 0; i < CH; ++i){ int idx = base + i; if (idx < n) s += cnt[idx]; }
  sums[tid] = s; __syncthreads();
  for (int d = 1; d < 256; d <<= 1){
    int v = (tid >= d) ? sums[tid - d] : 0;
    __syncthreads();
    sums[tid] += v;
    __syncthreads();
  }
  int run = (tid == 0) ? 0 : sums[tid - 1];
  for (int i = 0; i < CH; ++i){
    int idx = base + i;
    if (idx < n){ off[idx] = run; run += cnt[idx]; }
  }
  if (tid == 0) off[n] = sums[255];
}

__global__ __launch_bounds__(256) void scatter_kernel(const int* __restrict__ ei, const float* __restrict__ dis,
                                                      const int* __restrict__ off, int* __restrict__ cursor,
                                                      int2* __restrict__ pe, int E){
  int e = blockIdx.x*256 + threadIdx.x;
  if (e < E){
    int r = ei[e];
    int c = ei[E + e];
    int pos = off[c] + atomicAdd(&cursor[c], 1);
    pe[pos] = make_int2(r, __float_as_int(dis[r]*dis[c]));
  }
}

// ---------------- layer-1 GRU chain: ONE kernel, fused x@Wih + h@Whh ----------------
// grid 157, block 512 = 8 waves (2 row-groups x 4 col-groups of 32x64cols).
// Block owns 64 rows for all 24 t. h: f16 LDS tile (MFMA A) + f32 LDS tile (exact state).
// No GI buffer: x read f32 direct (coalesced), weights from L2.
__global__ __launch_bounds__(512, 2) void gru1_chain_kernel(
    const float* __restrict__ x, const f16* __restrict__ Wih,
    const f16* __restrict__ Whh, const float* __restrict__ bih,
    const float* __restrict__ bhh, f16* __restrict__ h1all)
{
  constexpr int H   = H1C;     // 256
  constexpr int LP  = H + 8;   // 264 f16: rows 528B (16B-aligned), 132 dw stride -> low conflict
  constexpr int LP32= H + 4;   // 260 f32
  __shared__ __align__(16) f16   hl[64*LP];     // 33.8 KB
  __shared__ __align__(16) float hs[64*LP32];   // 66.6 KB

  const int tid  = threadIdx.x;
  const int lane = tid & 63;
  const int w    = tid >> 6;        // 0..7
  const int wm   = w >> 2;          // 0..1 row group
  const int wc   = w & 3;           // 0..3 col group
  const int lr   = lane & 15;
  const int lk8  = (lane >> 4)*8;
  const int r0   = (lane >> 4)*4;
  const int row_base = blockIdx.x*64;

  for (int k = tid*8; k < 64*LP; k += 512*8)
    *(f16x8*)&hl[k] = (f16x8){0,0,0,0,0,0,0,0};
  for (int k = tid*4; k < 64*LP32; k += 512*4)
    *(float4*)&hs[k] = make_float4(0.f,0.f,0.f,0.f);

  int lrow[2], aoffx[2];
  #pragma unroll
  for (int mi = 0; mi < 2; ++mi){
    lrow[mi] = wm*32 + mi*16 + lr;
    int g0 = row_base + lrow[mi]; if (g0 >= NN) g0 = NN-1;
    aoffx[mi] = g0*DIN + lk8;
  }
  int colv[4], bxo[4][3], bho[4][3];
  float bR[4], bZ[4], bNi[4], bNh[4];
  #pragma unroll
  for (int ci = 0; ci < 4; ++ci){
    const int col = wc*64 + ci*16 + lr;
    colv[ci] = col;
    #pragma unroll
    for (int g = 0; g < 3; ++g){
      bxo[ci][g] = (g*H + col)*DIN + lk8;
      bho[ci][g] = (g*H + col)*H   + lk8;
    }
    bR[ci]  = bih[col]       + bhh[col];
    bZ[ci]  = bih[H+col]     + bhh[H+col];
    bNi[ci] = bih[2*H+col];
    bNh[ci] = bhh[2*H+col];
  }
  __syncthreads();

  for (int t = 0; t < TT; ++t){
    const float* xt = x + (size_t)t*NN*DIN;
    f32x4 acc[2][4][4] = {};   // [mi][ci][0=r,1=z,2=n_x,3=n_h]

    // x part, K = 128 (fp32 global, coalesced 16B/lane, in-reg cvt)
    #pragma unroll
    for (int k0 = 0; k0 < DIN; k0 += 32){
      f16x8 a[2], b[4][3];
      #pragma unroll
      for (int mi = 0; mi < 2; ++mi) a[mi] = cvt8(xt + aoffx[mi] + k0);
      #pragma unroll
      for (int ci = 0; ci < 4; ++ci)
        #pragma unroll
        for (int g = 0; g < 3; ++g) b[ci][g] = *(const f16x8*)(Wih + bxo[ci][g] + k0);
      #pragma unroll
      for (int mi = 0; mi < 2; ++mi)
        #pragma unroll
        for (int ci = 0; ci < 4; ++ci){
          acc[mi][ci][0] = __builtin_amdgcn_mfma_f32_16x16x32_f16(a[mi], b[ci][0], acc[mi][ci][0], 0,0,0);
          acc[mi][ci][1] = __builtin_amdgcn_mfma_f32_16x16x32_f16(a[mi], b[ci][1], acc[mi][ci][1], 0,0,0);
          acc[mi][ci][2] = __builtin_amdgcn_mfma_f32_16x16x32_f16(a[mi], b[ci][2], acc[mi][ci][2], 0,0,0);
        }
    }
    // h part, K = 256 (f16 LDS tile)
    #pragma unroll
    for (int k0 = 0; k0 < H; k0 += 32){
      f16x8 a[2], b[4][3];
      #pragma unroll
      for (int mi = 0; mi < 2; ++mi) a[mi] = *(const f16x8*)&hl[lrow[mi]*LP + k0 + lk8];
      #pragma unroll
      for (int ci = 0; ci < 4; ++ci)
        #pragma unroll
        for (int g = 0; g < 3; ++g) b[ci][g] = *(const f16x8*)(Whh + bho[ci][g] + k0);
      #pragma unroll
      for (int mi = 0; mi < 2; ++mi)
        #pragma unroll
        for (int ci = 0; ci < 4; ++ci){
          acc[mi][ci][0] = __builtin_amdgcn_mfma_f32_16x16x32_f16(a[mi], b[ci][0], acc[mi][ci][0], 0,0,0);
          acc[mi][ci][1] = __builtin_amdgcn_mfma_f32_16x16x32_f16(a[mi], b[ci][1], acc[mi][ci][1], 0,0,0);
          acc[mi][ci][3] = __builtin_amdgcn_mfma_f32_16x16x32_f16(a[mi], b[ci][2], acc[mi][ci][3], 0,0,0);
        }
    }
    __syncthreads();   // all reads of hl done
    // epilogue: gates + fp32 state (LDS) + f16 tile update
    #pragma unroll
    for (int mi = 0; mi < 2; ++mi){
      #pragma unroll
      for (int rr = 0; rr < 4; ++rr){
        const int rl = wm*32 + mi*16 + r0 + rr;
        #pragma unroll
        for (int ci = 0; ci < 4; ++ci){
          const int col = colv[ci];
          const float rg = sigmoidf_(acc[mi][ci][0][rr] + bR[ci]);
          const float zg = sigmoidf_(acc[mi][ci][1][rr] + bZ[ci]);
          const float ng = tanhf(acc[mi][ci][2][rr] + bNi[ci] + rg*(acc[mi][ci][3][rr] + bNh[ci]));
          const float hv = (1.0f - zg)*ng + zg*hs[rl*LP32 + col];
          hs[rl*LP32 + col] = hv;
          hl[rl*LP + col]   = (f16)hv;
        }
      }
    }
    __syncthreads();   // epilogue writes visible
    // coalesced copy LDS f16 tile -> h1all[t]  (64 rows x 32 chunks of 16B)
    f16* ho = h1all + ((size_t)t*NN + row_base)*H;
    #pragma unroll
    for (int c = 0; c < 4; ++c){
      const int idx = c*512 + tid;         // 0..2047
      const int row = idx >> 5, seg = idx & 31;
      if (row_base + row < NN)
        *(f16x8*)&ho[(size_t)row*H + seg*8] = *(const f16x8*)&hl[row*LP + seg*8];
    }
    // next K-loop only reads hl; next epilogue writes are fenced by its own barrier
  }
}

// ---------------- layer-2 GRU chain: ONE kernel, fused x2@Wih2 + h@Whh2 ----------------
// grid 157, block 512 = 8 waves (2 row-groups x 4 col-groups of 32x32cols).
__global__ __launch_bounds__(512, 2) void gru2_chain_kernel(
    const f16* __restrict__ x2all, const f16* __restrict__ Wih,
    const f16* __restrict__ Whh, const float* __restrict__ bih,
    const float* __restrict__ bhh, float* __restrict__ h2fin)
{
  constexpr int H  = H2C;     // 128
  constexpr int KX = H1C;     // 256
  constexpr int LP = H + 8;   // 136
  __shared__ __align__(16) f16 hl[64*LP];   // 17.4 KB

  const int tid  = threadIdx.x;
  const int lane = tid & 63;
  const int w    = tid >> 6;
  const int wm   = w >> 2;          // 0..1
  const int wc   = w & 3;           // 0..3
  const int lr   = lane & 15;
  const int lk8  = (lane >> 4)*8;
  const int r0   = (lane >> 4)*4;
  const int row_base = blockIdx.x*64;

  for (int k = tid*8; k < 64*LP; k += 512*8)
    *(f16x8*)&hl[k] = (f16x8){0,0,0,0,0,0,0,0};

  int lrow[2], aoffx[2];
  #pragma unroll
  for (int mi = 0; mi < 2; ++mi){
    lrow[mi] = wm*32 + mi*16 + lr;
    int g0 = row_base + lrow[mi]; if (g0 >= NN) g0 = NN-1;
    aoffx[mi] = g0*KX + lk8;
  }
  int colv[2], bxo[2][3], bho[2][3];
  float bR[2], bZ[2], bNi[2], bNh[2];
  #pragma unroll
  for (int ci = 0; ci < 2; ++ci){
    const int col = wc*32 + ci*16 + lr;
    colv[ci] = col;
    #pragma unroll
    for (int g = 0; g < 3; ++g){
      bxo[ci][g] = (g*H + col)*KX + lk8;
      bho[ci][g] = (g*H + col)*H  + lk8;
    }
    bR[ci]  = bih[col]       + bhh[col];
    bZ[ci]  = bih[H+col]     + bhh[H+col];
    bNi[ci] = bih[2*H+col];
    bNh[ci] = bhh[2*H+col];
  }
  float hst[2][4][2] = {};   // fp32 state in registers (small here)
  __syncthreads();

  for (int t = 0; t < TT; ++t){
    const f16* xt = x2all + (size_t)t*NN*KX;
    f32x4 acc[2][2][4] = {};

    // x2 part, K = 256 (f16 global, coalesced)
    #pragma unroll
    for (int k0 = 0; k0 < KX; k0 += 32){
      f16x8 a[2], b[2][3];
      #pragma unroll
      for (int mi = 0; mi < 2; ++mi) a[mi] = *(const f16x8*)(xt + aoffx[mi] + k0);
      #pragma unroll
      for (int ci = 0; ci < 2; ++ci)
        #pragma unroll
        for (int g = 0; g < 3; ++g) b[ci][g] = *(const f16x8*)(Wih + bxo[ci][g] + k0);
      #pragma unroll
      for (int mi = 0; mi < 2; ++mi)
        #pragma unroll
        for (int ci = 0; ci < 2; ++ci){
          acc[mi][ci][0] = __builtin_amdgcn_mfma_f32_16x16x32_f16(a[mi], b[ci][0], acc[mi][ci][0], 0,0,0);
          acc[mi][ci][1] = __builtin_amdgcn_mfma_f32_16x16x32_f16(a[mi], b[ci][1], acc[mi][ci][1], 0,0,0);
          acc[mi][ci][2] = __builtin_amdgcn_mfma_f32_16x16x32_f16(a[mi], b[ci][2], acc[mi][ci][2], 0,0,0);
        }
    }
    // h part, K = 128 (LDS)
    #pragma unroll
    for (int k0 = 0; k0 < H; k0 += 32){
      f16x8 a[2], b[2][3];
      #pragma unroll
      for (int mi = 0; mi < 2; ++mi) a[mi] = *(const f16x8*)&hl[lrow[mi]*LP + k0 + lk8];
      #pragma unroll
      for (int ci = 0; ci < 2; ++ci)
        #pragma unroll
        for (int g = 0; g < 3; ++g) b[ci][g] = *(const f16x8*)(Whh + bho[ci][g] + k0);
      #pragma unroll
      for (int mi = 0; mi < 2; ++mi)
        #pragma unroll
        for (int ci = 0; ci < 2; ++ci){
          acc[mi][ci][0] = __builtin_amdgcn_mfma_f32_16x16x32_f16(a[mi], b[ci][0], acc[mi][ci][0], 0,0,0);
          acc[mi][ci][1] = __builtin_amdgcn_mfma_f32_16x16x32_f16(a[mi], b[ci][1], acc[mi][ci][1], 0,0,0);
          acc[mi][ci][3] = __builtin_amdgcn_mfma_f32_16x16x32_f16(a[mi], b[ci][2], acc[mi][ci][3], 0,0,0);
        }
    }
    __syncthreads();
    #pragma unroll
    for (int mi = 0; mi < 2; ++mi){
      #pragma unroll
      for (int rr = 0; rr < 4; ++rr){
        const int rl = wm*32 + mi*16 + r0 + rr;
        const int growu = row_base + rl;
        #pragma unroll
        for (int ci = 0; ci < 2; ++ci){
          const int col = colv[ci];
          const float rg = sigmoidf_(acc[mi][ci][0][rr] + bR[ci]);
          const float zg = sigmoidf_(acc[mi][ci][1][rr] + bZ[ci]);
          const float ng = tanhf(acc[mi][ci][2][rr] + bNi[ci] + rg*(acc[mi][ci][3][rr] + bNh[ci]));
          const float hv = (1.0f - zg)*ng + zg*hst[mi][rr][ci];
          hst[mi][rr][ci] = hv;
          hl[rl*LP + col] = (f16)hv;
          if (t == TT-1 && growu < NN)
            h2fin[(size_t)growu*H + col] = hv;
        }
      }
    }
    __syncthreads();
  }
}

// ---------------- batched graph conv: 8 nodes/block, XCD-pinned t-slices ----------------
// grid = 30000 (8 xcd x 3 tq x 1250), block 512 = 8 warps, warp = one node, f16x4/lane.
__global__ __launch_bounds__(512) void conv1_kernel(
    const f16* __restrict__ hall, const int2* __restrict__ pe,
    const int* __restrict__ off, const float* __restrict__ dis,
    const float* __restrict__ bias, f16* __restrict__ outall)
{
  const int b   = blockIdx.x;
  const int xcd = b & 7;
  const int v   = b >> 3;            // 0..3749
  const int tq  = v / 1250;          // 0..2
  const int t   = xcd + 8*tq;
  const int i   = (v - tq*1250)*8 + (threadIdx.x >> 6);
  const int f   = threadIdx.x & 63;  // f16x4 index
  const f16x4* hp = (const f16x4*)(hall + (size_t)t*NN*H1C);
  const float d = dis[i];
  const f16x4 sv = hp[(size_t)i*64 + f];
  float a0 = d*d*(float)sv[0];
  float a1 = d*d*(float)sv[1];
  float a2 = d*d*(float)sv[2];
  float a3 = d*d*(float)sv[3];
  int e = off[i]; const int e2 = off[i+1];
  for (; e + 8 <= e2; e += 8){
    int2 q[8];
    #pragma unroll
    for (int u = 0; u < 8; ++u) q[u] = pe[e+u];
    #pragma unroll
    for (int u = 0; u < 8; ++u){
      const float wq = __int_as_float(q[u].y);
      const f16x4 vv = hp[(size_t)q[u].x*64 + f];
      a0 += wq*(float)vv[0]; a1 += wq*(float)vv[1];
      a2 += wq*(float)vv[2]; a3 += wq*(float)vv[3];
    }
  }
  for (; e < e2; ++e){
    const int2 q = pe[e];
    const float wq = __int_as_float(q.y);
    const f16x4 vv = hp[(size_t)q.x*64 + f];
    a0 += wq*(float)vv[0]; a1 += wq*(float)vv[1];
    a2 += wq*(float)vv[2]; a3 += wq*(float)vv[3];
  }
  const float4 bb = ((const float4*)bias)[f];
  a0 = fmaxf(a0 + bb.x, 0.0f);
  a1 = fmaxf(a1 + bb.y, 0.0f);
  a2 = fmaxf(a2 + bb.z, 0.0f);
  a3 = fmaxf(a3 + bb.w, 0.0f);
  f16x4 o; o[0]=(f16)a0; o[1]=(f16)a1; o[2]=(f16)a2; o[3]=(f16)a3;
  ((f16x4*)(outall + (size_t)t*NN*H1C))[(size_t)i*64 + f] = o;
}

// conv2: H=128, single t, fp32 in/out
__global__ __launch_bounds__(64) void conv2_kernel(
    const float* __restrict__ h, const int2* __restrict__ pe,
    const int* __restrict__ off, const float* __restrict__ dis,
    const float* __restrict__ bias, float* __restrict__ out)
{
  const int i = blockIdx.x;
  const int f = threadIdx.x;            // float2 index
  const float2* hp = (const float2*)h;
  const float d = dis[i];
  const float2 sv = hp[(size_t)i*64 + f];
  float a0 = d*d*sv.x;
  float a1 = d*d*sv.y;
  int e = off[i]; const int e2 = off[i+1];
  for (; e + 4 <= e2; e += 4){
    int2 q[4];
    #pragma unroll
    for (int u = 0; u < 4; ++u) q[u] = pe[e+u];
    #pragma unroll
    for (int u = 0; u < 4; ++u){
      const float wq = __int_as_float(q[u].y);
      const float2 vv = hp[(size_t)q[u].x*64 + f];
      a0 += wq*vv.x; a1 += wq*vv.y;
    }
  }
  for (; e < e2; ++e){
    const int2 q = pe[e];
    const float wq = __int_as_float(q.y);
    const float2 vv = hp[(size_t)q.x*64 + f];
    a0 += wq*vv.x; a1 += wq*vv.y;
  }
  const float2 bb = ((const float2*)bias)[f];
  ((float2*)out)[(size_t)i*64 + f] = make_float2(a0 + bb.x, a1 + bb.y);
}

// ---------------- final dense + softmax ----------------
__global__ __launch_bounds__(256) void dense_kernel(const float* __restrict__ flat,
    const float* __restrict__ linW, float* __restrict__ logits)
{
  const int j   = blockIdx.x;
  const int tid = threadIdx.x;
  const int Q4  = FLATSZ/4;                  // 320000
  const int CH4 = Q4/64;                     // 5000 (gridDim.y == 64)
  const int s4  = blockIdx.y*CH4;
  const int e4  = s4 + CH4;
  const float4* w4 = (const float4*)&linW[(size_t)j*FLATSZ];
  const float4* f4 = (const float4*)flat;
  float part = 0.0f;
  for (int i = s4 + tid; i < e4; i += 256){
    const float4 a = w4[i];
    const float4 b = f4[i];
    part += a.x*b.x + a.y*b.y + a.z*b.z + a.w*b.w;
  }
  __shared__ float red[256];
  red[tid] = part; __syncthreads();
  for (int s = 128; s > 0; s >>= 1){
    if (tid < s) red[tid] += red[tid + s];
    __syncthreads();
  }
  if (tid == 0) atomicAdd(&logits[j], red[0]);
}

__global__ __launch_bounds__(128) void softmax_kernel(const float* __restrict__ logits,
    const float* __restrict__ linb, float* __restrict__ out)
{
  __shared__ float red[128];
  const int tid = threadIdx.x;
  const float v = (tid < OUTD) ? logits[tid] + linb[tid] : -INFINITY;
  red[tid] = v; __syncthreads();
  for (int s = 64; s > 0; s >>= 1){
    if (tid < s) red[tid] = fmaxf(red[tid], red[tid + s]);
    __syncthreads();
  }
  const float mx = red[0]; __syncthreads();
  const float e = (tid < OUTD) ? expf(v - mx) : 0.0f;
  red[tid] = e; __syncthreads();
  for (int s = 64; s > 0; s >>= 1){
    if (tid < s) red[tid] += red[tid + s];
    __syncthreads();
  }
  const float inv = 1.0f/red[0];
  if (tid < OUTD) out[tid] = e*inv;
}

// ---------------- launch ----------------

extern "C" void kernel_launch(void* const* d_in, const int* in_sizes, int n_in,
                              void* d_out, int out_size, void* d_ws, size_t ws_size,
                              hipStream_t stream)
{
  const float* x     = (const float*)d_in[0];
  const int*   ei    = (const int*)  d_in[1];
  const float* W_ih1 = (const float*)d_in[2];
  const float* W_hh1 = (const float*)d_in[3];
  const float* b_ih1 = (const float*)d_in[4];
  const float* b_hh1 = (const float*)d_in[5];
  const float* bias1 = (const float*)d_in[6];
  const float* W_ih2 = (const float*)d_in[7];
  const float* W_hh2 = (const float*)d_in[8];
  const float* b_ih2 = (const float*)d_in[9];
  const float* b_hh2 = (const float*)d_in[10];
  const float* bias2 = (const float*)d_in[11];
  const float* lin_W = (const float*)d_in[12];
  const float* lin_b = (const float*)d_in[13];
  float* out = (float*)d_out;
  const int E = in_sizes[1]/2;
  (void)n_in; (void)out_size; (void)ws_size;

  char* p = (char*)d_ws;
  auto alloc = [&](size_t bytes)->void* {
    void* r = (void*)p;
    p += (bytes + 255) & ~(size_t)255;
    return r;
  };
  int*   cnt    = (int*)  alloc((size_t)NN*4);
  int*   cursor = (int*)  alloc((size_t)NN*4);
  int*   offs   = (int*)  alloc((size_t)(NN+1)*4);
  float* dis    = (float*)alloc((size_t)NN*4);
  int2*  pe     = (int2*) alloc((size_t)E*8);
  f16*   h1all  = (f16*)  alloc((size_t)TT*NN*H1C*2);   // 123 MB
  f16*   x2all  = (f16*)  alloc((size_t)TT*NN*H1C*2);   // 123 MB
  float* h2fin  = (float*)alloc((size_t)NN*H2C*4);
  float* out2   = (float*)alloc((size_t)NN*H2C*4);
  f16*   wih1h  = (f16*)  alloc((size_t)3*H1C*DIN*2);
  f16*   whh1h  = (f16*)  alloc((size_t)3*H1C*H1C*2);
  f16*   wih2h  = (f16*)  alloc((size_t)3*H2C*H1C*2);
  f16*   whh2h  = (f16*)  alloc((size_t)3*H2C*H2C*2);
  float* logits = (float*)alloc((size_t)OUTD*4);

  // ---- graph preprocessing ----
  init_kernel   <<<(NN+255)/256, 256, 0, stream>>>(cnt, cursor, logits, NN);
  count_kernel  <<<(E+255)/256, 256, 0, stream>>>(ei, cnt, E);
  dis_kernel    <<<(NN+255)/256, 256, 0, stream>>>(cnt, dis, NN);
  scan_kernel   <<<1, 256, 0, stream>>>(cnt, offs, NN);
  scatter_kernel<<<(E+255)/256, 256, 0, stream>>>(ei, dis, offs, cursor, pe, E);

  // ---- f16 weight casts ----
  cast_f16_kernel<<<((3*H1C*DIN/4)+255)/256, 256, 0, stream>>>((const float4*)W_ih1, (f16x4*)wih1h, 3*H1C*DIN/4);
  cast_f16_kernel<<<((3*H1C*H1C/4)+255)/256, 256, 0, stream>>>((const float4*)W_hh1, (f16x4*)whh1h, 3*H1C*H1C/4);
  cast_f16_kernel<<<((3*H2C*H1C/4)+255)/256, 256, 0, stream>>>((const float4*)W_ih2, (f16x4*)wih2h, 3*H2C*H1C/4);
  cast_f16_kernel<<<((3*H2C*H2C/4)+255)/256, 256, 0, stream>>>((const float4*)W_hh2, (f16x4*)whh2h, 3*H2C*H2C/4);

  const int CB = (NN + 63)/64;   // 157

  // ---- layer-1 chain: fused x@Wih1 + h@Whh1, 24 steps inside ----
  gru1_chain_kernel<<<CB, 512, 0, stream>>>(x, wih1h, whh1h, b_ih1, b_hh1, h1all);

  // ---- batched conv1 (XCD-pinned, 8 nodes/block) ----
  conv1_kernel<<<24*NN/8, 512, 0, stream>>>(h1all, pe, offs, dis, bias1, x2all);

  // ---- layer-2 chain: fused x2@Wih2 + h@Whh2 ----
  gru2_chain_kernel<<<CB, 512, 0, stream>>>(x2all, wih2h, whh2h, b_ih2, b_hh2, h2fin);

  conv2_kernel<<<NN, 64, 0, stream>>>(h2fin, pe, offs, dis, bias2, out2);
  dense_kernel<<<dim3(OUTD, 64), 256, 0, stream>>>(out2, lin_W, logits);
  softmax_kernel<<<1, 128, 0, stream>>>(logits, lin_b, out);
}

// Round 11
// 1760.519 us; speedup vs baseline: 1.5975x; 1.4164x over previous
//
#include <hip/hip_runtime.h>
#include <math.h>

#define TT   24
#define NN   10000
#define DIN  128
#define H1C  256
#define H2C  128
#define OUTD 100
#define FLATSZ (NN*H2C)

typedef _Float16 f16;
typedef _Float16 f16x4 __attribute__((ext_vector_type(4)));
typedef _Float16 f16x8 __attribute__((ext_vector_type(8)));
typedef float    f32x4 __attribute__((ext_vector_type(4)));
typedef int      i32x2 __attribute__((ext_vector_type(2)));

__device__ __forceinline__ float sigmoidf_(float x){ return 1.0f/(1.0f+expf(-x)); }

// ---------------- small utility kernels ----------------

__global__ __launch_bounds__(256) void cast_f16_kernel(const float4* __restrict__ in,
                                                       f16x4* __restrict__ out, int n4){
  int i = blockIdx.x*256 + threadIdx.x;
  if (i < n4){
    float4 v = in[i];
    f16x4 o; o[0]=(f16)v.x; o[1]=(f16)v.y; o[2]=(f16)v.z; o[3]=(f16)v.w;
    out[i] = o;
  }
}

__global__ __launch_bounds__(256) void init_kernel(int* __restrict__ cnt, int* __restrict__ cursor,
                                                   float* __restrict__ logits, int n){
  int i = blockIdx.x*256 + threadIdx.x;
  if (i < n){ cnt[i] = 0; cursor[i] = 0; }
  if (i < OUTD) logits[i] = 0.0f;
}

__global__ __launch_bounds__(256) void count_kernel(const int* __restrict__ ei, int* __restrict__ cnt, int E){
  int e = blockIdx.x*256 + threadIdx.x;
  if (e < E) atomicAdd(&cnt[ei[E + e]], 1);
}

__global__ __launch_bounds__(256) void dis_kernel(const int* __restrict__ cnt, float* __restrict__ dis, int n){
  int i = blockIdx.x*256 + threadIdx.x;
  if (i < n) dis[i] = rsqrtf((float)(cnt[i] + 1));   // +1 self-loop
}

__global__ __launch_bounds__(256) void scan_kernel(const int* __restrict__ cnt, int* __restrict__ off, int n){
  __shared__ int sums[256];
  const int tid = threadIdx.x;
  const int CH  = 40;
  const int base = tid*CH;
  int s = 0;
  for (int i = 0; i < CH; ++i){ int idx = base + i; if (idx < n) s += cnt[idx]; }
  sums[tid] = s; __syncthreads();
  for (int d = 1; d < 256; d <<= 1){
    int v = (tid >= d) ? sums[tid - d] : 0;
    __syncthreads();
    sums[tid] += v;
    __syncthreads();
  }
  int run = (tid == 0) ? 0 : sums[tid - 1];
  for (int i = 0; i < CH; ++i){
    int idx = base + i;
    if (idx < n){ off[idx] = run; run += cnt[idx]; }
  }
  if (tid == 0) off[n] = sums[255];
}

__global__ __launch_bounds__(256) void scatter_kernel(const int* __restrict__ ei, const float* __restrict__ dis,
                                                      const int* __restrict__ off, int* __restrict__ cursor,
                                                      int2* __restrict__ pe, int E){
  int e = blockIdx.x*256 + threadIdx.x;
  if (e < E){
    int r = ei[e];
    int c = ei[E + e];
    int pos = off[c] + atomicAdd(&cursor[c], 1);
    pe[pos] = make_int2(r, __float_as_int(dis[r]*dis[c]));
  }
}

// ---------------- layer-1 GRU chain: ONE kernel, waves = 8 col-groups x 64 rows ----------------
// Block owns 64 rows, all 24 t. Weights read ONCE per block-step (wave w owns cols w*32..+32).
// x staged to LDS per step (nt loads). h: f16 LDS tile + fp32 register state. h1all written nt.
__global__ __launch_bounds__(512, 2) void gru1_chain_kernel(
    const float* __restrict__ x, const f16* __restrict__ Wih,
    const f16* __restrict__ Whh, const float* __restrict__ bih,
    const float* __restrict__ bhh, f16* __restrict__ h1all)
{
  constexpr int H  = H1C;      // 256
  constexpr int LP = H + 8;    // 264 f16 pitch (hl)
  constexpr int XP = DIN + 8;  // 136 f16 pitch (xl)
  __shared__ __align__(16) f16 hl[64*LP];   // 33.8 KB
  __shared__ __align__(16) f16 xl[64*XP];   // 17.4 KB

  const int tid  = threadIdx.x;
  const int lane = tid & 63;
  const int w    = tid >> 6;        // 0..7 col group (32 cols each)
  const int lr   = lane & 15;
  const int lk8  = (lane >> 4)*8;
  const int r0   = (lane >> 4)*4;
  const int row_base = blockIdx.x*64;

  for (int k = tid*8; k < 64*LP; k += 512*8)
    *(f16x8*)&hl[k] = (f16x8){0,0,0,0,0,0,0,0};

  int lrow[4];
  #pragma unroll
  for (int mi = 0; mi < 4; ++mi) lrow[mi] = mi*16 + lr;

  int colv[2], bxo[2][3], bho[2][3];
  float bR[2], bZ[2], bNi[2], bNh[2];
  #pragma unroll
  for (int ci = 0; ci < 2; ++ci){
    const int col = w*32 + ci*16 + lr;
    colv[ci] = col;
    #pragma unroll
    for (int g = 0; g < 3; ++g){
      bxo[ci][g] = (g*H + col)*DIN + lk8;
      bho[ci][g] = (g*H + col)*H   + lk8;
    }
    bR[ci]  = bih[col]       + bhh[col];
    bZ[ci]  = bih[H+col]     + bhh[H+col];
    bNi[ci] = bih[2*H+col];
    bNh[ci] = bhh[2*H+col];
  }

  float hst[4][4][2] = {};   // [mi][rr][ci] fp32 state, thread-owned across t
  __syncthreads();

  for (int t = 0; t < TT; ++t){
    // ---- stage x tile (64 rows x 128 f32 -> f16), nt loads ----
    {
      const float* xg = x + (size_t)t*NN*DIN;
      #pragma unroll
      for (int s = 0; s < 4; ++s){
        const int idx = s*512 + tid;       // 0..2047
        const int row = idx >> 5;
        const int c4  = (idx & 31)*4;
        int gr = row_base + row; if (gr >= NN) gr = NN-1;
        const f32x4 v = __builtin_nontemporal_load((const f32x4*)&xg[(size_t)gr*DIN + c4]);
        f16x4 o; o[0]=(f16)v[0]; o[1]=(f16)v[1]; o[2]=(f16)v[2]; o[3]=(f16)v[3];
        *(f16x4*)&xl[row*XP + c4] = o;
      }
    }
    __syncthreads();   // xl ready; hl stable

    f32x4 acc[4][2][4] = {};   // [mi][ci][0=r,1=z,2=n_x,3=n_h]

    // x part, K = 128 (A from LDS)
    #pragma unroll
    for (int k0 = 0; k0 < DIN; k0 += 32){
      f16x8 a[4], b[2][3];
      #pragma unroll
      for (int mi = 0; mi < 4; ++mi) a[mi] = *(const f16x8*)&xl[lrow[mi]*XP + k0 + lk8];
      #pragma unroll
      for (int ci = 0; ci < 2; ++ci)
        #pragma unroll
        for (int g = 0; g < 3; ++g) b[ci][g] = *(const f16x8*)(Wih + bxo[ci][g] + k0);
      #pragma unroll
      for (int mi = 0; mi < 4; ++mi)
        #pragma unroll
        for (int ci = 0; ci < 2; ++ci){
          acc[mi][ci][0] = __builtin_amdgcn_mfma_f32_16x16x32_f16(a[mi], b[ci][0], acc[mi][ci][0], 0,0,0);
          acc[mi][ci][1] = __builtin_amdgcn_mfma_f32_16x16x32_f16(a[mi], b[ci][1], acc[mi][ci][1], 0,0,0);
          acc[mi][ci][2] = __builtin_amdgcn_mfma_f32_16x16x32_f16(a[mi], b[ci][2], acc[mi][ci][2], 0,0,0);
        }
    }
    // h part, K = 256 (A from LDS)
    #pragma unroll
    for (int k0 = 0; k0 < H; k0 += 32){
      f16x8 a[4], b[2][3];
      #pragma unroll
      for (int mi = 0; mi < 4; ++mi) a[mi] = *(const f16x8*)&hl[lrow[mi]*LP + k0 + lk8];
      #pragma unroll
      for (int ci = 0; ci < 2; ++ci)
        #pragma unroll
        for (int g = 0; g < 3; ++g) b[ci][g] = *(const f16x8*)(Whh + bho[ci][g] + k0);
      #pragma unroll
      for (int mi = 0; mi < 4; ++mi)
        #pragma unroll
        for (int ci = 0; ci < 2; ++ci){
          acc[mi][ci][0] = __builtin_amdgcn_mfma_f32_16x16x32_f16(a[mi], b[ci][0], acc[mi][ci][0], 0,0,0);
          acc[mi][ci][1] = __builtin_amdgcn_mfma_f32_16x16x32_f16(a[mi], b[ci][1], acc[mi][ci][1], 0,0,0);
          acc[mi][ci][3] = __builtin_amdgcn_mfma_f32_16x16x32_f16(a[mi], b[ci][2], acc[mi][ci][3], 0,0,0);
        }
    }
    __syncthreads();   // all reads of hl/xl done
    // epilogue: gates + register state + hl update
    #pragma unroll
    for (int mi = 0; mi < 4; ++mi){
      #pragma unroll
      for (int rr = 0; rr < 4; ++rr){
        const int rl = mi*16 + r0 + rr;
        #pragma unroll
        for (int ci = 0; ci < 2; ++ci){
          const int col = colv[ci];
          const float rg = sigmoidf_(acc[mi][ci][0][rr] + bR[ci]);
          const float zg = sigmoidf_(acc[mi][ci][1][rr] + bZ[ci]);
          const float ng = tanhf(acc[mi][ci][2][rr] + bNi[ci] + rg*(acc[mi][ci][3][rr] + bNh[ci]));
          const float hv = (1.0f - zg)*ng + zg*hst[mi][rr][ci];
          hst[mi][rr][ci] = hv;
          hl[rl*LP + col] = (f16)hv;
        }
      }
    }
    __syncthreads();   // hl updated
    // coalesced nt copy LDS -> h1all[t]
    f16* ho = h1all + ((size_t)t*NN + row_base)*H;
    #pragma unroll
    for (int c = 0; c < 4; ++c){
      const int idx = c*512 + tid;         // 0..2047
      const int row = idx >> 5, seg = idx & 31;
      if (row_base + row < NN)
        __builtin_nontemporal_store(*(const f16x8*)&hl[row*LP + seg*8],
                                    (f16x8*)&ho[(size_t)row*H + seg*8]);
    }
    // copy reads of hl complete before next epilogue writes (stage barrier + K-loop barrier intervene)
  }
}

// ---------------- layer-2 GRU chain: waves = 8 col-groups x 16 cols, 64 rows ----------------
__global__ __launch_bounds__(512, 2) void gru2_chain_kernel(
    const f16* __restrict__ x2all, const f16* __restrict__ Wih,
    const f16* __restrict__ Whh, const float* __restrict__ bih,
    const float* __restrict__ bhh, float* __restrict__ h2fin)
{
  constexpr int H   = H2C;     // 128
  constexpr int KX  = H1C;     // 256
  constexpr int LP  = H + 8;   // 136
  constexpr int X2P = KX + 8;  // 264
  __shared__ __align__(16) f16 hl[64*LP];    // 17.4 KB
  __shared__ __align__(16) f16 x2l[64*X2P];  // 33.8 KB

  const int tid  = threadIdx.x;
  const int lane = tid & 63;
  const int w    = tid >> 6;        // 0..7 col group (16 cols each)
  const int lr   = lane & 15;
  const int lk8  = (lane >> 4)*8;
  const int r0   = (lane >> 4)*4;
  const int row_base = blockIdx.x*64;

  for (int k = tid*8; k < 64*LP; k += 512*8)
    *(f16x8*)&hl[k] = (f16x8){0,0,0,0,0,0,0,0};

  int lrow[4];
  #pragma unroll
  for (int mi = 0; mi < 4; ++mi) lrow[mi] = mi*16 + lr;

  const int col = w*16 + lr;
  int bxo[3], bho[3];
  #pragma unroll
  for (int g = 0; g < 3; ++g){
    bxo[g] = (g*H + col)*KX + lk8;
    bho[g] = (g*H + col)*H  + lk8;
  }
  const float bR  = bih[col]       + bhh[col];
  const float bZ  = bih[H+col]     + bhh[H+col];
  const float bNi = bih[2*H+col];
  const float bNh = bhh[2*H+col];

  float hst[4][4] = {};   // [mi][rr]
  __syncthreads();

  for (int t = 0; t < TT; ++t){
    // ---- stage x2 tile (64 rows x 256 f16), nt loads ----
    {
      const f16* xg = x2all + (size_t)t*NN*KX;
      #pragma unroll
      for (int s = 0; s < 4; ++s){
        const int idx = s*512 + tid;       // 0..2047
        const int row = idx >> 5;
        const int sg  = (idx & 31)*8;
        int gr = row_base + row; if (gr >= NN) gr = NN-1;
        f16x8 v = __builtin_nontemporal_load((const f16x8*)&xg[(size_t)gr*KX + sg]);
        *(f16x8*)&x2l[row*X2P + sg] = v;
      }
    }
    __syncthreads();

    f32x4 acc[4][4] = {};   // [mi][0=r,1=z,2=n_x,3=n_h]

    // x2 part, K = 256 (A from LDS)
    #pragma unroll
    for (int k0 = 0; k0 < KX; k0 += 32){
      f16x8 a[4], b[3];
      #pragma unroll
      for (int mi = 0; mi < 4; ++mi) a[mi] = *(const f16x8*)&x2l[lrow[mi]*X2P + k0 + lk8];
      #pragma unroll
      for (int g = 0; g < 3; ++g) b[g] = *(const f16x8*)(Wih + bxo[g] + k0);
      #pragma unroll
      for (int mi = 0; mi < 4; ++mi){
        acc[mi][0] = __builtin_amdgcn_mfma_f32_16x16x32_f16(a[mi], b[0], acc[mi][0], 0,0,0);
        acc[mi][1] = __builtin_amdgcn_mfma_f32_16x16x32_f16(a[mi], b[1], acc[mi][1], 0,0,0);
        acc[mi][2] = __builtin_amdgcn_mfma_f32_16x16x32_f16(a[mi], b[2], acc[mi][2], 0,0,0);
      }
    }
    // h part, K = 128 (A from LDS)
    #pragma unroll
    for (int k0 = 0; k0 < H; k0 += 32){
      f16x8 a[4], b[3];
      #pragma unroll
      for (int mi = 0; mi < 4; ++mi) a[mi] = *(const f16x8*)&hl[lrow[mi]*LP + k0 + lk8];
      #pragma unroll
      for (int g = 0; g < 3; ++g) b[g] = *(const f16x8*)(Whh + bho[g] + k0);
      #pragma unroll
      for (int mi = 0; mi < 4; ++mi){
        acc[mi][0] = __builtin_amdgcn_mfma_f32_16x16x32_f16(a[mi], b[0], acc[mi][0], 0,0,0);
        acc[mi][1] = __builtin_amdgcn_mfma_f32_16x16x32_f16(a[mi], b[1], acc[mi][1], 0,0,0);
        acc[mi][3] = __builtin_amdgcn_mfma_f32_16x16x32_f16(a[mi], b[2], acc[mi][3], 0,0,0);
      }
    }
    __syncthreads();
    #pragma unroll
    for (int mi = 0; mi < 4; ++mi){
      #pragma unroll
      for (int rr = 0; rr < 4; ++rr){
        const int rl = mi*16 + r0 + rr;
        const int growu = row_base + rl;
        const float rg = sigmoidf_(acc[mi][0][rr] + bR);
        const float zg = sigmoidf_(acc[mi][1][rr] + bZ);
        const float ng = tanhf(acc[mi][2][rr] + bNi + rg*(acc[mi][3][rr] + bNh));
        const float hv = (1.0f - zg)*ng + zg*hst[mi][rr];
        hst[mi][rr] = hv;
        hl[rl*LP + col] = (f16)hv;
        if (t == TT-1 && growu < NN)
          h2fin[(size_t)growu*H + col] = hv;
      }
    }
    __syncthreads();
  }
}

// ---------------- batched graph conv: 8 nodes/block, XCD-pinned t-slices ----------------
__global__ __launch_bounds__(512) void conv1_kernel(
    const f16* __restrict__ hall, const int2* __restrict__ pe,
    const int* __restrict__ off, const float* __restrict__ dis,
    const float* __restrict__ bias, f16* __restrict__ outall)
{
  const int b   = blockIdx.x;
  const int xcd = b & 7;
  const int v   = b >> 3;            // 0..3749
  const int tq  = v / 1250;          // 0..2
  const int t   = xcd + 8*tq;
  const int i   = (v - tq*1250)*8 + (threadIdx.x >> 6);
  const int f   = threadIdx.x & 63;  // f16x4 index
  const f16x4* hp = (const f16x4*)(hall + (size_t)t*NN*H1C);
  const float d = dis[i];
  const f16x4 sv = hp[(size_t)i*64 + f];
  float a0 = d*d*(float)sv[0];
  float a1 = d*d*(float)sv[1];
  float a2 = d*d*(float)sv[2];
  float a3 = d*d*(float)sv[3];
  int e = off[i]; const int e2 = off[i+1];
  const i32x2* pev = (const i32x2*)pe;
  for (; e + 8 <= e2; e += 8){
    i32x2 q[8];
    #pragma unroll
    for (int u = 0; u < 8; ++u) q[u] = __builtin_nontemporal_load(&pev[e+u]);
    #pragma unroll
    for (int u = 0; u < 8; ++u){
      const float wq = __int_as_float(q[u][1]);
      const f16x4 vv = hp[(size_t)q[u][0]*64 + f];
      a0 += wq*(float)vv[0]; a1 += wq*(float)vv[1];
      a2 += wq*(float)vv[2]; a3 += wq*(float)vv[3];
    }
  }
  for (; e < e2; ++e){
    const int2 q = pe[e];
    const float wq = __int_as_float(q.y);
    const f16x4 vv = hp[(size_t)q.x*64 + f];
    a0 += wq*(float)vv[0]; a1 += wq*(float)vv[1];
    a2 += wq*(float)vv[2]; a3 += wq*(float)vv[3];
  }
  const float4 bb = ((const float4*)bias)[f];
  a0 = fmaxf(a0 + bb.x, 0.0f);
  a1 = fmaxf(a1 + bb.y, 0.0f);
  a2 = fmaxf(a2 + bb.z, 0.0f);
  a3 = fmaxf(a3 + bb.w, 0.0f);
  f16x4 o; o[0]=(f16)a0; o[1]=(f16)a1; o[2]=(f16)a2; o[3]=(f16)a3;
  __builtin_nontemporal_store(o, (f16x4*)(outall + (size_t)t*NN*H1C) + (size_t)i*64 + f);
}

// conv2: H=128, single t, fp32 in/out
__global__ __launch_bounds__(64) void conv2_kernel(
    const float* __restrict__ h, const int2* __restrict__ pe,
    const int* __restrict__ off, const float* __restrict__ dis,
    const float* __restrict__ bias, float* __restrict__ out)
{
  const int i = blockIdx.x;
  const int f = threadIdx.x;            // float2 index
  const float2* hp = (const float2*)h;
  const float d = dis[i];
  const float2 sv = hp[(size_t)i*64 + f];
  float a0 = d*d*sv.x;
  float a1 = d*d*sv.y;
  int e = off[i]; const int e2 = off[i+1];
  for (; e + 4 <= e2; e += 4){
    int2 q[4];
    #pragma unroll
    for (int u = 0; u < 4; ++u) q[u] = pe[e+u];
    #pragma unroll
    for (int u = 0; u < 4; ++u){
      const float wq = __int_as_float(q[u].y);
      const float2 vv = hp[(size_t)q[u].x*64 + f];
      a0 += wq*vv.x; a1 += wq*vv.y;
    }
  }
  for (; e < e2; ++e){
    const int2 q = pe[e];
    const float wq = __int_as_float(q.y);
    const float2 vv = hp[(size_t)q.x*64 + f];
    a0 += wq*vv.x; a1 += wq*vv.y;
  }
  const float2 bb = ((const float2*)bias)[f];
  ((float2*)out)[(size_t)i*64 + f] = make_float2(a0 + bb.x, a1 + bb.y);
}

// ---------------- final dense + softmax ----------------
__global__ __launch_bounds__(256) void dense_kernel(const float* __restrict__ flat,
    const float* __restrict__ linW, float* __restrict__ logits)
{
  const int j   = blockIdx.x;
  const int tid = threadIdx.x;
  const int Q4  = FLATSZ/4;                  // 320000
  const int CH4 = Q4/64;                     // 5000 (gridDim.y == 64)
  const int s4  = blockIdx.y*CH4;
  const int e4  = s4 + CH4;
  const f32x4* w4 = (const f32x4*)&linW[(size_t)j*FLATSZ];
  const float4* f4 = (const float4*)flat;
  float part = 0.0f;
  for (int i = s4 + tid; i < e4; i += 256){
    const f32x4 a = __builtin_nontemporal_load(&w4[i]);
    const float4 b = f4[i];
    part += a[0]*b.x + a[1]*b.y + a[2]*b.z + a[3]*b.w;
  }
  __shared__ float red[256];
  red[tid] = part; __syncthreads();
  for (int s = 128; s > 0; s >>= 1){
    if (tid < s) red[tid] += red[tid + s];
    __syncthreads();
  }
  if (tid == 0) atomicAdd(&logits[j], red[0]);
}

__global__ __launch_bounds__(128) void softmax_kernel(const float* __restrict__ logits,
    const float* __restrict__ linb, float* __restrict__ out)
{
  __shared__ float red[128];
  const int tid = threadIdx.x;
  const float v = (tid < OUTD) ? logits[tid] + linb[tid] : -INFINITY;
  red[tid] = v; __syncthreads();
  for (int s = 64; s > 0; s >>= 1){
    if (tid < s) red[tid] = fmaxf(red[tid], red[tid + s]);
    __syncthreads();
  }
  const float mx = red[0]; __syncthreads();
  const float e = (tid < OUTD) ? expf(v - mx) : 0.0f;
  red[tid] = e; __syncthreads();
  for (int s = 64; s > 0; s >>= 1){
    if (tid < s) red[tid] += red[tid + s];
    __syncthreads();
  }
  const float inv = 1.0f/red[0];
  if (tid < OUTD) out[tid] = e*inv;
}

// ---------------- launch ----------------

extern "C" void kernel_launch(void* const* d_in, const int* in_sizes, int n_in,
                              void* d_out, int out_size, void* d_ws, size_t ws_size,
                              hipStream_t stream)
{
  const float* x     = (const float*)d_in[0];
  const int*   ei    = (const int*)  d_in[1];
  const float* W_ih1 = (const float*)d_in[2];
  const float* W_hh1 = (const float*)d_in[3];
  const float* b_ih1 = (const float*)d_in[4];
  const float* b_hh1 = (const float*)d_in[5];
  const float* bias1 = (const float*)d_in[6];
  const float* W_ih2 = (const float*)d_in[7];
  const float* W_hh2 = (const float*)d_in[8];
  const float* b_ih2 = (const float*)d_in[9];
  const float* b_hh2 = (const float*)d_in[10];
  const float* bias2 = (const float*)d_in[11];
  const float* lin_W = (const float*)d_in[12];
  const float* lin_b = (const float*)d_in[13];
  float* out = (float*)d_out;
  const int E = in_sizes[1]/2;
  (void)n_in; (void)out_size; (void)ws_size;

  char* p = (char*)d_ws;
  auto alloc = [&](size_t bytes)->void* {
    void* r = (void*)p;
    p += (bytes + 255) & ~(size_t)255;
    return r;
  };
  int*   cnt    = (int*)  alloc((size_t)NN*4);
  int*   cursor = (int*)  alloc((size_t)NN*4);
  int*   offs   = (int*)  alloc((size_t)(NN+1)*4);
  float* dis    = (float*)alloc((size_t)NN*4);
  int2*  pe     = (int2*) alloc((size_t)E*8);
  f16*   h1all  = (f16*)  alloc((size_t)TT*NN*H1C*2);   // 123 MB
  f16*   x2all  = (f16*)  alloc((size_t)TT*NN*H1C*2);   // 123 MB
  float* h2fin  = (float*)alloc((size_t)NN*H2C*4);
  float* out2   = (float*)alloc((size_t)NN*H2C*4);
  f16*   wih1h  = (f16*)  alloc((size_t)3*H1C*DIN*2);
  f16*   whh1h  = (f16*)  alloc((size_t)3*H1C*H1C*2);
  f16*   wih2h  = (f16*)  alloc((size_t)3*H2C*H1C*2);
  f16*   whh2h  = (f16*)  alloc((size_t)3*H2C*H2C*2);
  float* logits = (float*)alloc((size_t)OUTD*4);

  // ---- graph preprocessing ----
  init_kernel   <<<(NN+255)/256, 256, 0, stream>>>(cnt, cursor, logits, NN);
  count_kernel  <<<(E+255)/256, 256, 0, stream>>>(ei, cnt, E);
  dis_kernel    <<<(NN+255)/256, 256, 0, stream>>>(cnt, dis, NN);
  scan_kernel   <<<1, 256, 0, stream>>>(cnt, offs, NN);
  scatter_kernel<<<(E+255)/256, 256, 0, stream>>>(ei, dis, offs, cursor, pe, E);

  // ---- f16 weight casts ----
  cast_f16_kernel<<<((3*H1C*DIN/4)+255)/256, 256, 0, stream>>>((const float4*)W_ih1, (f16x4*)wih1h, 3*H1C*DIN/4);
  cast_f16_kernel<<<((3*H1C*H1C/4)+255)/256, 256, 0, stream>>>((const float4*)W_hh1, (f16x4*)whh1h, 3*H1C*H1C/4);
  cast_f16_kernel<<<((3*H2C*H1C/4)+255)/256, 256, 0, stream>>>((const float4*)W_ih2, (f16x4*)wih2h, 3*H2C*H1C/4);
  cast_f16_kernel<<<((3*H2C*H2C/4)+255)/256, 256, 0, stream>>>((const float4*)W_hh2, (f16x4*)whh2h, 3*H2C*H2C/4);

  const int CB = (NN + 63)/64;   // 157

  // ---- layer-1 chain ----
  gru1_chain_kernel<<<CB, 512, 0, stream>>>(x, wih1h, whh1h, b_ih1, b_hh1, h1all);

  // ---- batched conv1 (XCD-pinned, 8 nodes/block) ----
  conv1_kernel<<<24*NN/8, 512, 0, stream>>>(h1all, pe, offs, dis, bias1, x2all);

  // ---- layer-2 chain ----
  gru2_chain_kernel<<<CB, 512, 0, stream>>>(x2all, wih2h, whh2h, b_ih2, b_hh2, h2fin);

  conv2_kernel<<<NN, 64, 0, stream>>>(h2fin, pe, offs, dis, bias2, out2);
  dense_kernel<<<dim3(OUTD, 64), 256, 0, stream>>>(out2, lin_W, logits);
  softmax_kernel<<<1, 128, 0, stream>>>(logits, lin_b, out);
}